// Round 6
// baseline (572.626 us; speedup 1.0000x reference)
//
#include <hip/hip_runtime.h>
#include <math.h>

#define EPSBN 1e-5f
#define STAT_NCH 128

typedef _Float16 half8 __attribute__((ext_vector_type(8)));
typedef _Float16 half4v __attribute__((ext_vector_type(4)));
typedef float floatx4 __attribute__((ext_vector_type(4)));

// ------------------------------------------------ KNN (top-16), 8-way chunked
// (round-4 version: 94 KB LDS, no VGPR cap — measured 111 us)
__global__ __launch_bounds__(512) void knn_kernel(const float* __restrict__ x,
                                                  int* __restrict__ idx)
{
    __shared__ float xs[2048], ys[2048], sq[2048];
    __shared__ float md[8][64][17];
    __shared__ int   mi[8][64][17];
    int b  = blockIdx.x >> 5;              // 32 blocks per batch
    int q0 = (blockIdx.x & 31) << 6;       // 64 queries per block
    const float* xb = x + (size_t)b * 2048 * 10;
    for (int j = threadIdx.x; j < 2048; j += 512) {
        float xj = xb[j * 10 + 0], yj = xb[j * 10 + 1];
        xs[j] = xj; ys[j] = yj;
        sq[j] = __fadd_rn(__fmul_rn(xj, xj), __fmul_rn(yj, yj));
    }
    __syncthreads();
    int lane = threadIdx.x & 63;
    int chunk = threadIdx.x >> 6;          // 0..7
    int i = q0 + lane;                     // query index within batch
    float xi = xs[i], yi = ys[i], sqi = sq[i];
    float bd[16]; int bi[16];
#pragma unroll
    for (int s = 0; s < 16; ++s) { bd[s] = INFINITY; bi[s] = 0; }
    int j0 = chunk << 8;
    for (int jj = 0; jj < 256; ++jj) {
        int j = j0 + jj;
        float dot = __fadd_rn(__fmul_rn(xi, xs[j]), __fmul_rn(yi, ys[j]));
        float d   = __fsub_rn(__fadd_rn(sqi, sq[j]), __fmul_rn(2.0f, dot));
        if (j == i) d = INFINITY;
        if (d < bd[15]) {                  // strict < : ties keep lower index
            bd[15] = d; bi[15] = j;
#pragma unroll
            for (int s = 15; s > 0; --s) {
                if (bd[s] < bd[s - 1]) {
                    float td = bd[s]; bd[s] = bd[s - 1]; bd[s - 1] = td;
                    int   ti = bi[s]; bi[s] = bi[s - 1]; bi[s - 1] = ti;
                }
            }
        }
    }
#pragma unroll
    for (int s = 0; s < 16; ++s) { md[chunk][lane][s] = bd[s]; mi[chunk][lane][s] = bi[s]; }
    __syncthreads();
    if (threadIdx.x < 64) {
        int q = threadIdx.x;
        float fd[16]; int fi[16];
#pragma unroll
        for (int s = 0; s < 16; ++s) { fd[s] = INFINITY; fi[s] = 0; }
        for (int c = 0; c < 8; ++c) {
            for (int s = 0; s < 16; ++s) {
                float d = md[c][q][s];
                if (!(d < fd[15])) break;  // sorted list: rest can't qualify
                int j = mi[c][q][s];
                fd[15] = d; fi[15] = j;
#pragma unroll
                for (int t = 15; t > 0; --t) {
                    if (fd[t] < fd[t - 1]) {
                        float td = fd[t]; fd[t] = fd[t - 1]; fd[t - 1] = td;
                        int   ti = fi[t]; fi[t] = fi[t - 1]; fi[t - 1] = ti;
                    }
                }
            }
        }
        int* out = idx + (size_t)(b * 2048 + q0 + q) * 16;
#pragma unroll
        for (int s = 0; s < 16; ++s) out[s] = fi[s];
    }
}

// ------------------------------------------------- covariance + 19-ch feature
__global__ __launch_bounds__(256) void cov_feat_kernel(const float* __restrict__ x,
                                                       const int* __restrict__ idx,
                                                       float* __restrict__ f19)
{
    int p = blockIdx.x * 256 + threadIdx.x;   // 0..16383
    int b = p >> 11;
    const float* xr = x + (size_t)p * 10;
    float v0 = xr[0], v1 = xr[1], v2 = xr[2], v3 = xr[3], v4 = xr[4];
    float v5 = xr[5], v6 = xr[6], v7 = xr[7], v8 = xr[8], v9 = xr[9];
    float e = v2 + v3 + v4 + v5 + v6 + v7 + v8 + v9;
    float sx = v0, sy = v1, se = e;
    float sxx = v0 * v0, sxy = v0 * v1, sxe = v0 * e;
    float syy = v1 * v1, sye = v1 * e, see = e * e;
    const int* ir = idx + (size_t)p * 16;
    const float* xb = x + ((size_t)(b << 11)) * 10;
#pragma unroll
    for (int k = 0; k < 16; ++k) {
        int nj = ir[k];
        const float* nr = xb + (size_t)nj * 10;
        float nx = nr[0], ny = nr[1];
        float ne = nr[2] + nr[3] + nr[4] + nr[5] + nr[6] + nr[7] + nr[8] + nr[9];
        sx += nx; sy += ny; se += ne;
        sxx += nx * nx; sxy += nx * ny; sxe += nx * ne;
        syy += ny * ny; sye += ny * ne; see += ne * ne;
    }
    const float inv = 1.0f / 17.0f;
    float mx = sx * inv, my = sy * inv, me = se * inv;
    float cxx = sxx * inv - mx * mx, cxy = sxy * inv - mx * my, cxe = sxe * inv - mx * me;
    float cyy = syy * inv - my * my, cye = sye * inv - my * me, cee = see * inv - me * me;
    float* o = f19 + (size_t)p * 19;
    o[0] = v0; o[1] = v1; o[2] = v2; o[3] = v3; o[4] = v4;
    o[5] = v5; o[6] = v6; o[7] = v7; o[8] = v8; o[9] = v9;
    o[10] = cxx; o[11] = cxy; o[12] = cxe;
    o[13] = cxy; o[14] = cyy; o[15] = cye;
    o[16] = cxe; o[17] = cye; o[18] = cee;
}

// ------------------------------------------------------------- 19->64 GEMM
__global__ __launch_bounds__(256) void lin19_kernel(const float* __restrict__ f19,
                                                    const float* __restrict__ w,
                                                    float* __restrict__ out)
{
    __shared__ float ws_[19 * 64];
    __shared__ float fr[4 * 19];
    int t = threadIdx.x;
    for (int i = t; i < 19 * 64; i += 256) ws_[i] = w[i];
    int p0 = blockIdx.x * 4;
    for (int i = t; i < 4 * 19; i += 256) fr[i] = f19[(size_t)p0 * 19 + i];
    __syncthreads();
    int lp = t >> 6, c = t & 63;
    float acc = 0.f;
#pragma unroll
    for (int k = 0; k < 19; ++k) acc = fmaf(fr[lp * 19 + k], ws_[k * 64 + c], acc);
    out[(size_t)(p0 + lp) * 64 + c] = acc;
}

// ------------- fp32 tiled GEMM + fused input-BN-ReLU + fused col-stats
// C[M,64] = relu(A*asc+ash) @ B[64,64]; per-block column sum/sumsq partials.
__global__ __launch_bounds__(256) void gemm_bn_kernel(const float* __restrict__ A,
                                                      const float* __restrict__ B,
                                                      float* __restrict__ C,
                                                      const float* __restrict__ asc,
                                                      const float* __restrict__ ash,
                                                      float* __restrict__ ps,
                                                      float* __restrict__ pq,
                                                      int M, int N, int K)
{
    __shared__ float As[16][64];   // [k][row]
    __shared__ float Bs[16][64];   // [k][col]
    __shared__ float ssc[64], ssh[64];
    int t  = threadIdx.x;
    if (t < 64) { ssc[t] = asc[t]; ssh[t] = ash[t]; }
    int m0 = blockIdx.y << 6, n0 = blockIdx.x << 6;
    int arow = t >> 2, acol = (t & 3) << 2;
    int brow = t >> 4, bcol = (t & 15) << 2;
    int tr = (t >> 4) << 2, tc = (t & 15) << 2;
    float acc[4][4] = {};
    for (int k0 = 0; k0 < K; k0 += 16) {
        float4 av = *(const float4*)(A + (size_t)(m0 + arow) * K + k0 + acol);
        float4 bv = *(const float4*)(B + (size_t)(k0 + brow) * N + n0 + bcol);
        __syncthreads();
        int ka = k0 + acol;
        As[acol + 0][arow] = fmaxf(fmaf(av.x, ssc[ka + 0], ssh[ka + 0]), 0.f);
        As[acol + 1][arow] = fmaxf(fmaf(av.y, ssc[ka + 1], ssh[ka + 1]), 0.f);
        As[acol + 2][arow] = fmaxf(fmaf(av.z, ssc[ka + 2], ssh[ka + 2]), 0.f);
        As[acol + 3][arow] = fmaxf(fmaf(av.w, ssc[ka + 3], ssh[ka + 3]), 0.f);
        *(float4*)&Bs[brow][bcol] = bv;
        __syncthreads();
#pragma unroll
        for (int kk = 0; kk < 16; ++kk) {
            float4 a = *(const float4*)&As[kk][tr];
            float4 bb = *(const float4*)&Bs[kk][tc];
            float ar[4] = {a.x, a.y, a.z, a.w};
            float br[4] = {bb.x, bb.y, bb.z, bb.w};
#pragma unroll
            for (int i = 0; i < 4; ++i)
#pragma unroll
                for (int j = 0; j < 4; ++j)
                    acc[i][j] = fmaf(ar[i], br[j], acc[i][j]);
        }
    }
#pragma unroll
    for (int i = 0; i < 4; ++i) {
        float4 o;
        o.x = acc[i][0]; o.y = acc[i][1]; o.z = acc[i][2]; o.w = acc[i][3];
        *(float4*)(C + (size_t)(m0 + tr + i) * N + n0 + tc) = o;
    }
    // ---- fused column stats (per 64-row block) ----
    float cs[4], cq[4];
#pragma unroll
    for (int j = 0; j < 4; ++j) {
        cs[j] = acc[0][j] + acc[1][j] + acc[2][j] + acc[3][j];
        cq[j] = fmaf(acc[0][j], acc[0][j],
                fmaf(acc[1][j], acc[1][j],
                fmaf(acc[2][j], acc[2][j], acc[3][j] * acc[3][j])));
    }
    __syncthreads();
    float* sl = &As[0][0];   // [16][64]
    float* ql = &Bs[0][0];
    int rg = t >> 4;
#pragma unroll
    for (int j = 0; j < 4; ++j) { sl[rg * 64 + tc + j] = cs[j]; ql[rg * 64 + tc + j] = cq[j]; }
    __syncthreads();
    if (t < 64) {
        float s = 0.f, q = 0.f;
#pragma unroll
        for (int g = 0; g < 16; ++g) { s += sl[g * 64 + t]; q += ql[g * 64 + t]; }
        ps[(size_t)blockIdx.y * N + n0 + t] = s;
        pq[(size_t)blockIdx.y * N + n0 + t] = q;
    }
}

// ---------------- fp16 MFMA GEMM, 128x128 tile, f16 out + fused col-stats
__global__ __launch_bounds__(256) void hgemm_kernel(const _Float16* __restrict__ A,
                                                    const _Float16* __restrict__ BT,
                                                    _Float16* __restrict__ C,
                                                    float* __restrict__ ps,
                                                    float* __restrict__ pq,
                                                    int M, int N, int K)
{
    __shared__ __align__(16) _Float16 As[2][4][128][8];
    __shared__ __align__(16) _Float16 Bs[2][4][128][8];
    int t = threadIdx.x;
    int m0 = blockIdx.y << 7, n0 = blockIdx.x << 7;
    int wv = t >> 6, lane = t & 63;
    int fr = lane & 15, fk = lane >> 4;
    int srow = t & 63, sk8 = t >> 6;
    const _Float16* Ab = A + (size_t)m0 * K + sk8 * 8;
    const _Float16* Bb = BT + (size_t)n0 * K + sk8 * 8;

    floatx4 zero = {0.f, 0.f, 0.f, 0.f};
    floatx4 acc[2][8];
#pragma unroll
    for (int i = 0; i < 2; ++i)
#pragma unroll
        for (int j = 0; j < 8; ++j) acc[i][j] = zero;

    int NC = K >> 5;
    {
        uint4 a0 = *(const uint4*)(Ab + (size_t)srow * K);
        uint4 a1 = *(const uint4*)(Ab + (size_t)(srow + 64) * K);
        uint4 b0 = *(const uint4*)(Bb + (size_t)srow * K);
        uint4 b1 = *(const uint4*)(Bb + (size_t)(srow + 64) * K);
        *(uint4*)&As[0][sk8][srow][0]      = a0;
        *(uint4*)&As[0][sk8][srow + 64][0] = a1;
        *(uint4*)&Bs[0][sk8][srow][0]      = b0;
        *(uint4*)&Bs[0][sk8][srow + 64][0] = b1;
    }
    uint4 ra0, ra1, rb0, rb1;
    if (NC > 1) {
        ra0 = *(const uint4*)(Ab + (size_t)srow * K + 32);
        ra1 = *(const uint4*)(Ab + (size_t)(srow + 64) * K + 32);
        rb0 = *(const uint4*)(Bb + (size_t)srow * K + 32);
        rb1 = *(const uint4*)(Bb + (size_t)(srow + 64) * K + 32);
    }
    __syncthreads();

    for (int kc = 0; kc < NC; ++kc) {
        int cur = kc & 1;
        if (kc + 1 < NC) {
            int nx = cur ^ 1;
            *(uint4*)&As[nx][sk8][srow][0]      = ra0;
            *(uint4*)&As[nx][sk8][srow + 64][0] = ra1;
            *(uint4*)&Bs[nx][sk8][srow][0]      = rb0;
            *(uint4*)&Bs[nx][sk8][srow + 64][0] = rb1;
        }
        if (kc + 2 < NC) {
            int kb = (kc + 2) << 5;
            ra0 = *(const uint4*)(Ab + (size_t)srow * K + kb);
            ra1 = *(const uint4*)(Ab + (size_t)(srow + 64) * K + kb);
            rb0 = *(const uint4*)(Bb + (size_t)srow * K + kb);
            rb1 = *(const uint4*)(Bb + (size_t)(srow + 64) * K + kb);
        }
        half8 af[2];
#pragma unroll
        for (int mg = 0; mg < 2; ++mg)
            af[mg] = *(const half8*)&As[cur][fk][(wv << 5) + (mg << 4) + fr][0];
#pragma unroll
        for (int ng = 0; ng < 8; ++ng) {
            half8 bf = *(const half8*)&Bs[cur][fk][(ng << 4) + fr][0];
            acc[0][ng] = __builtin_amdgcn_mfma_f32_16x16x32_f16(af[0], bf, acc[0][ng], 0, 0, 0);
            acc[1][ng] = __builtin_amdgcn_mfma_f32_16x16x32_f16(af[1], bf, acc[1][ng], 0, 0, 0);
        }
        __syncthreads();
    }
    int orow = m0 + (wv << 5) + (fk << 2);
#pragma unroll
    for (int mg = 0; mg < 2; ++mg)
#pragma unroll
        for (int ng = 0; ng < 8; ++ng)
#pragma unroll
            for (int i = 0; i < 4; ++i)
                C[(size_t)(orow + (mg << 4) + i) * N + n0 + (ng << 4) + fr] =
                    (_Float16)acc[mg][ng][i];
    // ---- fused column stats (per 128-row block) on f32 accumulators ----
    float* sl = (float*)&As[0][0][0][0];   // [16][128]
    float* ql = (float*)&Bs[0][0][0][0];
    int cid = (wv << 2) + fk;              // 0..15
#pragma unroll
    for (int ng = 0; ng < 8; ++ng) {
        float s = 0.f, q = 0.f;
#pragma unroll
        for (int mg = 0; mg < 2; ++mg)
#pragma unroll
            for (int i = 0; i < 4; ++i) {
                float v = acc[mg][ng][i];
                s += v; q = fmaf(v, v, q);
            }
        sl[cid * 128 + (ng << 4) + fr] = s;
        ql[cid * 128 + (ng << 4) + fr] = q;
    }
    __syncthreads();
    if (t < 128) {
        float s = 0.f, q = 0.f;
#pragma unroll
        for (int g = 0; g < 16; ++g) { s += sl[g * 128 + t]; q += ql[g * 128 + t]; }
        ps[(size_t)blockIdx.y * N + n0 + t] = s;
        pq[(size_t)blockIdx.y * N + n0 + t] = q;
    }
}

// -------------------------------------- weight transpose+convert: wT[n][k]=w[k][n]
__global__ __launch_bounds__(256) void wtrans_kernel(const float* __restrict__ w,
                                                     _Float16* __restrict__ wT,
                                                     int K, int N)
{
    int id = blockIdx.x * 256 + threadIdx.x;
    if (id >= K * N) return;
    int k = id / N, n = id - k * N;
    wT[(size_t)n * K + k] = (_Float16)w[id];
}

// --------------------------------------------------- BN stats (f32 input, L1a)
__global__ __launch_bounds__(256) void stats_part_kernel(const float* __restrict__ X,
                                                         int C,
                                                         float* __restrict__ ps,
                                                         float* __restrict__ pq)
{
    __shared__ float sl[256][4];
    __shared__ float ql[256][4];
    int t = threadIdx.x;
    int c = (blockIdx.x << 6) + ((t & 15) << 2);
    int rowsPer = 16384 / STAT_NCH;
    int r0 = blockIdx.y * rowsPer + (t >> 4);
    int rEnd = blockIdx.y * rowsPer + rowsPer;
    float4 s = {0.f, 0.f, 0.f, 0.f}, q = {0.f, 0.f, 0.f, 0.f};
    for (int r = r0; r < rEnd; r += 16) {
        float4 v = *(const float4*)(X + (size_t)r * C + c);
        s.x += v.x; s.y += v.y; s.z += v.z; s.w += v.w;
        q.x = fmaf(v.x, v.x, q.x); q.y = fmaf(v.y, v.y, q.y);
        q.z = fmaf(v.z, v.z, q.z); q.w = fmaf(v.w, v.w, q.w);
    }
    sl[t][0] = s.x; sl[t][1] = s.y; sl[t][2] = s.z; sl[t][3] = s.w;
    ql[t][0] = q.x; ql[t][1] = q.y; ql[t][2] = q.z; ql[t][3] = q.w;
    __syncthreads();
    if (t < 64) {
        int comp = t & 3, grp = t >> 2;
        float ss = 0.f, qq = 0.f;
#pragma unroll
        for (int g = 0; g < 16; ++g) {
            ss += sl[grp + (g << 4)][comp];
            qq += ql[grp + (g << 4)][comp];
        }
        ps[(size_t)blockIdx.y * C + (blockIdx.x << 6) + t] = ss;
        pq[(size_t)blockIdx.y * C + (blockIdx.x << 6) + t] = qq;
    }
}

__global__ __launch_bounds__(64) void stats_fin_kernel(const float* __restrict__ ps,
                                                       const float* __restrict__ pq,
                                                       int C, int nch, float invM,
                                                       const float* __restrict__ g,
                                                       const float* __restrict__ bb,
                                                       float* __restrict__ scale,
                                                       float* __restrict__ shift)
{
    int c = blockIdx.x * 64 + threadIdx.x;
    float s = 0.f, q = 0.f;
    for (int ch = 0; ch < nch; ++ch) { s += ps[(size_t)ch * C + c]; q += pq[(size_t)ch * C + c]; }
    float m  = s * invM;
    float v  = fmaxf(q * invM - m * m, 0.f);
    float sc = g[c] / sqrtf(v + EPSBN);
    scale[c] = sc;
    shift[c] = bb[c] - m * sc;
}

// ------------- gather + bn on the fly + max + relu, C=64 f32 -> f16 output
__global__ __launch_bounds__(256) void gmax1_kernel(const float* __restrict__ f,
                                                    const float* __restrict__ scale,
                                                    const float* __restrict__ shift,
                                                    const int* __restrict__ idx,
                                                    _Float16* __restrict__ agg)
{
    int t = threadIdx.x;
    int p = blockIdx.x * 4 + (t >> 6);
    int c = t & 63;
    int b = p >> 11;
    float sc = scale[c], sh = shift[c];
    const int* ir = idx + (size_t)p * 16;
    const float* fb = f + ((size_t)(b << 11)) * 64;
    float m = -INFINITY;
#pragma unroll
    for (int k = 0; k < 16; ++k) {
        int nj = ir[k];
        m = fmaxf(m, fmaf(fb[(size_t)nj * 64 + c], sc, sh));
    }
    agg[(size_t)p * 64 + c] = (_Float16)fmaxf(m, 0.f);
}

// ------------- gather(f16) + bn on the fly + max + relu, C=512 -> f16 output
__global__ __launch_bounds__(256) void gmax2_kernel(const _Float16* __restrict__ f,
                                                    const float* __restrict__ scale,
                                                    const float* __restrict__ shift,
                                                    const int* __restrict__ idx,
                                                    _Float16* __restrict__ agg)
{
    int t = threadIdx.x;
    int p = blockIdx.x;
    int b = p >> 11;
    int c0 = t, c1 = t + 256;
    float s0 = scale[c0], h0 = shift[c0], s1 = scale[c1], h1 = shift[c1];
    const int* ir = idx + (size_t)p * 16;
    const _Float16* fb = f + ((size_t)(b << 11)) * 512;
    float m0 = -INFINITY, m1 = -INFINITY;
#pragma unroll
    for (int k = 0; k < 16; ++k) {
        int nj = ir[k];
        const _Float16* row = fb + (size_t)nj * 512;
        m0 = fmaxf(m0, fmaf((float)row[c0], s0, h0));
        m1 = fmaxf(m1, fmaf((float)row[c1], s1, h1));
    }
    _Float16* o = agg + (size_t)p * 512;
    o[c0] = (_Float16)fmaxf(m0, 0.f);
    o[c1] = (_Float16)fmaxf(m1, 0.f);
}

// ---------------- global max over N with bn applied (C=1024, f16 input)
__global__ __launch_bounds__(256) void globpart_kernel(const _Float16* __restrict__ f,
                                                       const float* __restrict__ scale,
                                                       const float* __restrict__ shift,
                                                       float* __restrict__ part)
{
    int c = blockIdx.x * 256 + threadIdx.x;
    int b = blockIdx.z, ch = blockIdx.y;
    float sc = scale[c], sh = shift[c];
    const _Float16* fb = f + ((size_t)(b << 11) + ch * 256) * 1024;
    float m = -INFINITY;
    for (int n = 0; n < 256; ++n)
        m = fmaxf(m, fmaf((float)fb[(size_t)n * 1024 + c], sc, sh));
    part[((size_t)(b * 8 + ch)) * 1024 + c] = m;
}

__global__ __launch_bounds__(256) void globred_kernel(const float* __restrict__ part,
                                                      float* __restrict__ glob)
{
    int c = blockIdx.x * 256 + threadIdx.x;
    int b = blockIdx.y;
    float m = -INFINITY;
#pragma unroll
    for (int ch = 0; ch < 8; ++ch)
        m = fmaxf(m, part[((size_t)(b * 8 + ch)) * 1024 + c]);
    glob[(size_t)b * 1024 + c] = m;
}

// ------------- final (8x1024)@(1024x512) + BN(8), 64 blocks (K-split x col-split)
__global__ __launch_bounds__(256) void final_kernel(const float* __restrict__ glob,
                                                    const float* __restrict__ w2,
                                                    const float* __restrict__ g,
                                                    const float* __restrict__ bb,
                                                    float* __restrict__ out)
{
    __shared__ float partial[8][8][4];
    __shared__ float vals[8][8];
    int t = threadIdx.x;
    int c8 = blockIdx.x << 3;              // 8 cols per block
    int r = t >> 5, c = (t >> 2) & 7, kq = t & 3;
    const float* gr = glob + (size_t)r * 1024 + (kq << 8);
    const float* wc = w2 + ((size_t)(kq << 8)) * 512 + c8 + c;
    float a = 0.f;
    for (int k = 0; k < 256; ++k)
        a = fmaf(gr[k], wc[(size_t)k * 512], a);
    partial[r][c][kq] = a;
    __syncthreads();
    if (t < 64) {
        int rr = t >> 3, cc = t & 7;
        vals[rr][cc] = partial[rr][cc][0] + partial[rr][cc][1]
                     + partial[rr][cc][2] + partial[rr][cc][3];
    }
    __syncthreads();
    if (t < 8) {
        int cc = t, cg = c8 + t;
        float s = 0.f;
#pragma unroll
        for (int rr = 0; rr < 8; ++rr) s += vals[rr][cc];
        float m = s * 0.125f;
        float v = 0.f;
#pragma unroll
        for (int rr = 0; rr < 8; ++rr) { float d = vals[rr][cc] - m; v = fmaf(d, d, v); }
        v *= 0.125f;
        float sc = g[cg] / sqrtf(v + EPSBN);
#pragma unroll
        for (int rr = 0; rr < 8; ++rr)
            out[(size_t)rr * 512 + cg] = fmaf(vals[rr][cc] - m, sc, bb[cg]);
    }
}

// =============================================================== launch
extern "C" void kernel_launch(void* const* d_in, const int* in_sizes, int n_in,
                              void* d_out, int out_size, void* d_ws, size_t ws_size,
                              hipStream_t stream)
{
    const float* x   = (const float*)d_in[0];
    const float* w1a = (const float*)d_in[1];
    const float* g1a = (const float*)d_in[2];
    const float* b1a = (const float*)d_in[3];
    const float* w1b = (const float*)d_in[4];
    const float* g1b = (const float*)d_in[5];
    const float* b1b = (const float*)d_in[6];
    const float* w1c = (const float*)d_in[7];
    const float* g1c = (const float*)d_in[8];
    const float* b1c = (const float*)d_in[9];
    const float* wg1 = (const float*)d_in[10];
    const float* gg1 = (const float*)d_in[11];
    const float* bg1 = (const float*)d_in[12];
    const float* wg2 = (const float*)d_in[13];
    const float* gg2 = (const float*)d_in[14];
    const float* bg2 = (const float*)d_in[15];
    const float* w2  = (const float*)d_in[16];
    const float* g2  = (const float*)d_in[17];
    const float* b2  = (const float*)d_in[18];

    char* w = (char*)d_ws;
    size_t off = 0;
    auto take = [&](size_t bytes) -> char* {
        char* p = w + off;
        off += (bytes + 255) & ~(size_t)255;
        return p;
    };
    int*       idx     = (int*)      take((size_t)16384 * 16 * 4);
    float*     f19     = (float*)    take((size_t)16384 * 19 * 4);
    float*     h0      = (float*)    take((size_t)16384 * 64 * 4);
    float*     h1      = (float*)    take((size_t)16384 * 64 * 4);
    float*     h2      = (float*)    take((size_t)16384 * 64 * 4);
    _Float16*  f512h   = (_Float16*) take((size_t)16384 * 512 * 2);
    _Float16*  f1024h  = (_Float16*) take((size_t)16384 * 1024 * 2);
    _Float16*  aggh64  = (_Float16*) take((size_t)16384 * 64 * 2);
    _Float16*  agg512h = (_Float16*) take((size_t)16384 * 512 * 2);
    _Float16*  w1T     = (_Float16*) take((size_t)512 * 64 * 2);
    _Float16*  w2T     = (_Float16*) take((size_t)1024 * 512 * 2);
    float*     ps      = (float*)    take((size_t)256 * 1024 * 4);
    float*     pq      = (float*)    take((size_t)256 * 1024 * 4);
    float* scA  = (float*)take(64 * 4);   float* shA  = (float*)take(64 * 4);
    float* scB  = (float*)take(64 * 4);   float* shB  = (float*)take(64 * 4);
    float* scC  = (float*)take(64 * 4);   float* shC  = (float*)take(64 * 4);
    float* scG1 = (float*)take(512 * 4);  float* shG1 = (float*)take(512 * 4);
    float* scG2 = (float*)take(1024 * 4); float* shG2 = (float*)take(1024 * 4);
    float* part = (float*)take((size_t)8 * 8 * 1024 * 4);
    float* glob = (float*)take((size_t)8 * 1024 * 4);
    (void)ws_size; (void)in_sizes; (void)n_in; (void)out_size;

    const float invM = 1.0f / 16384.0f;

    // weight conversions + knn up front
    wtrans_kernel<<<(64 * 512 + 255) / 256, 256, 0, stream>>>(wg1, w1T, 64, 512);
    wtrans_kernel<<<(512 * 1024 + 255) / 256, 256, 0, stream>>>(wg2, w2T, 512, 1024);
    knn_kernel<<<256, 512, 0, stream>>>(x, idx);
    cov_feat_kernel<<<64, 256, 0, stream>>>(x, idx, f19);

    // L1a: 19 -> 64 (raw out) + stats
    lin19_kernel<<<4096, 256, 0, stream>>>(f19, w1a, h0);
    stats_part_kernel<<<dim3(1, STAT_NCH), 256, 0, stream>>>(h0, 64, ps, pq);
    stats_fin_kernel<<<1, 64, 0, stream>>>(ps, pq, 64, STAT_NCH, invM, g1a, b1a, scA, shA);

    // L1b: bn_relu(h0) @ w1b -> h1 raw, fused stats
    gemm_bn_kernel<<<dim3(1, 256), 256, 0, stream>>>(h0, w1b, h1, scA, shA, ps, pq, 16384, 64, 64);
    stats_fin_kernel<<<1, 64, 0, stream>>>(ps, pq, 64, 256, invM, g1b, b1b, scB, shB);

    // L1c: bn_relu(h1) @ w1c -> h2 raw, fused stats
    gemm_bn_kernel<<<dim3(1, 256), 256, 0, stream>>>(h1, w1c, h2, scB, shB, ps, pq, 16384, 64, 64);
    stats_fin_kernel<<<1, 64, 0, stream>>>(ps, pq, 64, 256, invM, g1c, b1c, scC, shC);

    // graph pool 1: gather(bn(h2))-max-relu(f16), MFMA 64->512 (f16 out + stats)
    gmax1_kernel<<<4096, 256, 0, stream>>>(h2, scC, shC, idx, aggh64);
    hgemm_kernel<<<dim3(4, 128), 256, 0, stream>>>(aggh64, w1T, f512h, ps, pq, 16384, 512, 64);
    stats_fin_kernel<<<8, 64, 0, stream>>>(ps, pq, 512, 128, invM, gg1, bg1, scG1, shG1);

    // graph pool 2: gather(bn)-max-relu(f16), MFMA 512->1024 (f16 out + stats)
    gmax2_kernel<<<16384, 256, 0, stream>>>(f512h, scG1, shG1, idx, agg512h);
    hgemm_kernel<<<dim3(8, 128), 256, 0, stream>>>(agg512h, w2T, f1024h, ps, pq, 16384, 1024, 512);
    stats_fin_kernel<<<16, 64, 0, stream>>>(ps, pq, 1024, 128, invM, gg2, bg2, scG2, shG2);

    // global max over N with bn applied on the fly
    globpart_kernel<<<dim3(4, 8, 8), 256, 0, stream>>>(f1024h, scG2, shG2, part);
    globred_kernel<<<dim3(4, 8), 256, 0, stream>>>(part, glob);

    // final linear + BN over 8 rows
    final_kernel<<<64, 256, 0, stream>>>(glob, w2, g2, b2, (float*)d_out);
}

// Round 7
// 435.442 us; speedup vs baseline: 1.3150x; 1.3150x over previous
//
#include <hip/hip_runtime.h>
#include <math.h>

#define EPSBN 1e-5f
#define STAT_NCH 128

typedef _Float16 half8 __attribute__((ext_vector_type(8)));
typedef _Float16 half4v __attribute__((ext_vector_type(4)));
typedef float floatx4 __attribute__((ext_vector_type(4)));

// ---------------------------------------- KNN (top-16), 16-way chunked, 1024 thr
// 256 blocks x 1024 threads; 64 queries/block, 16 chunks of 128 candidates.
// LDS 128 KB -> 1 block/CU but 16 waves resident (4/SIMD).
__global__ void knn_kernel(const float* __restrict__ x,
                           int* __restrict__ idx)
{
    __shared__ float  xs[2048], ys[2048], sq[2048];   // 24 KB
    __shared__ float  md[16][64][17];                 // 68 KB, odd stride
    __shared__ ushort mi[16][64][18];                 // 36 KB, odd stride
    int b  = blockIdx.x >> 5;              // 32 blocks per batch
    int q0 = (blockIdx.x & 31) << 6;       // 64 queries per block
    const float* xb = x + (size_t)b * 2048 * 10;
    for (int j = threadIdx.x; j < 2048; j += 1024) {
        float xj = xb[j * 10 + 0], yj = xb[j * 10 + 1];
        xs[j] = xj; ys[j] = yj;
        sq[j] = __fadd_rn(__fmul_rn(xj, xj), __fmul_rn(yj, yj));
    }
    __syncthreads();
    int lane  = threadIdx.x & 63;
    int chunk = threadIdx.x >> 6;          // 0..15
    int i = q0 + lane;                     // query index within batch
    float xi = xs[i], yi = ys[i], sqi = sq[i];
    float bd[16]; int bi[16];
#pragma unroll
    for (int s = 0; s < 16; ++s) { bd[s] = INFINITY; bi[s] = 0; }
    int j0 = chunk << 7;                   // 128 candidates per chunk
    for (int jj = 0; jj < 128; ++jj) {
        int j = j0 + jj;
        float dot = __fadd_rn(__fmul_rn(xi, xs[j]), __fmul_rn(yi, ys[j]));
        float d   = __fsub_rn(__fadd_rn(sqi, sq[j]), __fmul_rn(2.0f, dot));
        if (j == i) d = INFINITY;
        if (d < bd[15]) {                  // strict < : ties keep lower index
            bd[15] = d; bi[15] = j;
#pragma unroll
            for (int s = 15; s > 0; --s) {
                if (bd[s] < bd[s - 1]) {
                    float td = bd[s]; bd[s] = bd[s - 1]; bd[s - 1] = td;
                    int   ti = bi[s]; bi[s] = bi[s - 1]; bi[s - 1] = ti;
                }
            }
        }
    }
#pragma unroll
    for (int s = 0; s < 16; ++s) { md[chunk][lane][s] = bd[s]; mi[chunk][lane][s] = (ushort)bi[s]; }
    __syncthreads();
    if (threadIdx.x < 64) {
        int q = threadIdx.x;
        float fd[16]; int fi[16];
#pragma unroll
        for (int s = 0; s < 16; ++s) { fd[s] = INFINITY; fi[s] = 0; }
        for (int c = 0; c < 16; ++c) {
            for (int s = 0; s < 16; ++s) {
                float d = md[c][q][s];
                if (!(d < fd[15])) break;  // sorted list: rest can't qualify
                int j = (int)mi[c][q][s];
                fd[15] = d; fi[15] = j;
#pragma unroll
                for (int t = 15; t > 0; --t) {
                    if (fd[t] < fd[t - 1]) {
                        float td = fd[t]; fd[t] = fd[t - 1]; fd[t - 1] = td;
                        int   ti = fi[t]; fi[t] = fi[t - 1]; fi[t - 1] = ti;
                    }
                }
            }
        }
        int* out = idx + (size_t)(b * 2048 + q0 + q) * 16;
#pragma unroll
        for (int s = 0; s < 16; ++s) out[s] = fi[s];
    }
}

// ------------------------------------------------- covariance + 19-ch feature
__global__ __launch_bounds__(256) void cov_feat_kernel(const float* __restrict__ x,
                                                       const int* __restrict__ idx,
                                                       float* __restrict__ f19)
{
    int p = blockIdx.x * 256 + threadIdx.x;   // 0..16383
    int b = p >> 11;
    const float* xr = x + (size_t)p * 10;
    float v0 = xr[0], v1 = xr[1], v2 = xr[2], v3 = xr[3], v4 = xr[4];
    float v5 = xr[5], v6 = xr[6], v7 = xr[7], v8 = xr[8], v9 = xr[9];
    float e = v2 + v3 + v4 + v5 + v6 + v7 + v8 + v9;
    float sx = v0, sy = v1, se = e;
    float sxx = v0 * v0, sxy = v0 * v1, sxe = v0 * e;
    float syy = v1 * v1, sye = v1 * e, see = e * e;
    const int* ir = idx + (size_t)p * 16;
    const float* xb = x + ((size_t)(b << 11)) * 10;
#pragma unroll
    for (int k = 0; k < 16; ++k) {
        int nj = ir[k];
        const float* nr = xb + (size_t)nj * 10;
        float nx = nr[0], ny = nr[1];
        float ne = nr[2] + nr[3] + nr[4] + nr[5] + nr[6] + nr[7] + nr[8] + nr[9];
        sx += nx; sy += ny; se += ne;
        sxx += nx * nx; sxy += nx * ny; sxe += nx * ne;
        syy += ny * ny; sye += ny * ne; see += ne * ne;
    }
    const float inv = 1.0f / 17.0f;
    float mx = sx * inv, my = sy * inv, me = se * inv;
    float cxx = sxx * inv - mx * mx, cxy = sxy * inv - mx * my, cxe = sxe * inv - mx * me;
    float cyy = syy * inv - my * my, cye = sye * inv - my * me, cee = see * inv - me * me;
    float* o = f19 + (size_t)p * 19;
    o[0] = v0; o[1] = v1; o[2] = v2; o[3] = v3; o[4] = v4;
    o[5] = v5; o[6] = v6; o[7] = v7; o[8] = v8; o[9] = v9;
    o[10] = cxx; o[11] = cxy; o[12] = cxe;
    o[13] = cxy; o[14] = cyy; o[15] = cye;
    o[16] = cxe; o[17] = cye; o[18] = cee;
}

// ------------------------------------------------------------- 19->64 GEMM
__global__ __launch_bounds__(256) void lin19_kernel(const float* __restrict__ f19,
                                                    const float* __restrict__ w,
                                                    float* __restrict__ out)
{
    __shared__ float ws_[19 * 64];
    __shared__ float fr[4 * 19];
    int t = threadIdx.x;
    for (int i = t; i < 19 * 64; i += 256) ws_[i] = w[i];
    int p0 = blockIdx.x * 4;
    for (int i = t; i < 4 * 19; i += 256) fr[i] = f19[(size_t)p0 * 19 + i];
    __syncthreads();
    int lp = t >> 6, c = t & 63;
    float acc = 0.f;
#pragma unroll
    for (int k = 0; k < 19; ++k) acc = fmaf(fr[lp * 19 + k], ws_[k * 64 + c], acc);
    out[(size_t)(p0 + lp) * 64 + c] = acc;
}

// ---------------------------------------------------- generic fp32 tiled GEMM
__global__ __launch_bounds__(256) void gemm_kernel(const float* __restrict__ A,
                                                   const float* __restrict__ B,
                                                   float* __restrict__ C,
                                                   int M, int N, int K)
{
    __shared__ float As[16][64];   // [k][row]
    __shared__ float Bs[16][64];   // [k][col]
    int t  = threadIdx.x;
    int m0 = blockIdx.y << 6, n0 = blockIdx.x << 6;
    int arow = t >> 2, acol = (t & 3) << 2;
    int brow = t >> 4, bcol = (t & 15) << 2;
    int tr = (t >> 4) << 2, tc = (t & 15) << 2;
    float acc[4][4] = {};
    for (int k0 = 0; k0 < K; k0 += 16) {
        float4 av = *(const float4*)(A + (size_t)(m0 + arow) * K + k0 + acol);
        float4 bv = *(const float4*)(B + (size_t)(k0 + brow) * N + n0 + bcol);
        __syncthreads();
        As[acol + 0][arow] = av.x; As[acol + 1][arow] = av.y;
        As[acol + 2][arow] = av.z; As[acol + 3][arow] = av.w;
        *(float4*)&Bs[brow][bcol] = bv;
        __syncthreads();
#pragma unroll
        for (int kk = 0; kk < 16; ++kk) {
            float4 a = *(const float4*)&As[kk][tr];
            float4 bb = *(const float4*)&Bs[kk][tc];
            float ar[4] = {a.x, a.y, a.z, a.w};
            float br[4] = {bb.x, bb.y, bb.z, bb.w};
#pragma unroll
            for (int i = 0; i < 4; ++i)
#pragma unroll
                for (int j = 0; j < 4; ++j)
                    acc[i][j] = fmaf(ar[i], br[j], acc[i][j]);
        }
    }
#pragma unroll
    for (int i = 0; i < 4; ++i) {
        float4 o;
        o.x = acc[i][0]; o.y = acc[i][1]; o.z = acc[i][2]; o.w = acc[i][3];
        *(float4*)(C + (size_t)(m0 + tr + i) * N + n0 + tc) = o;
    }
}

// ---------------------------------------------- fp16 MFMA GEMM, 128x128 tile
// A [M][K] f16 row-major, BT [N][K] f16 row-major, C [M][N] f16. K%32==0.
__global__ __launch_bounds__(256) void hgemm_kernel(const _Float16* __restrict__ A,
                                                    const _Float16* __restrict__ BT,
                                                    _Float16* __restrict__ C,
                                                    int M, int N, int K)
{
    __shared__ __align__(16) _Float16 As[2][4][128][8];
    __shared__ __align__(16) _Float16 Bs[2][4][128][8];
    int t = threadIdx.x;
    int m0 = blockIdx.y << 7, n0 = blockIdx.x << 7;
    int wv = t >> 6, lane = t & 63;
    int fr = lane & 15, fk = lane >> 4;
    int srow = t & 63, sk8 = t >> 6;
    const _Float16* Ab = A + (size_t)m0 * K + sk8 * 8;
    const _Float16* Bb = BT + (size_t)n0 * K + sk8 * 8;

    floatx4 zero = {0.f, 0.f, 0.f, 0.f};
    floatx4 acc[2][8];
#pragma unroll
    for (int i = 0; i < 2; ++i)
#pragma unroll
        for (int j = 0; j < 8; ++j) acc[i][j] = zero;

    int NC = K >> 5;
    {
        uint4 a0 = *(const uint4*)(Ab + (size_t)srow * K);
        uint4 a1 = *(const uint4*)(Ab + (size_t)(srow + 64) * K);
        uint4 b0 = *(const uint4*)(Bb + (size_t)srow * K);
        uint4 b1 = *(const uint4*)(Bb + (size_t)(srow + 64) * K);
        *(uint4*)&As[0][sk8][srow][0]      = a0;
        *(uint4*)&As[0][sk8][srow + 64][0] = a1;
        *(uint4*)&Bs[0][sk8][srow][0]      = b0;
        *(uint4*)&Bs[0][sk8][srow + 64][0] = b1;
    }
    uint4 ra0, ra1, rb0, rb1;
    if (NC > 1) {
        ra0 = *(const uint4*)(Ab + (size_t)srow * K + 32);
        ra1 = *(const uint4*)(Ab + (size_t)(srow + 64) * K + 32);
        rb0 = *(const uint4*)(Bb + (size_t)srow * K + 32);
        rb1 = *(const uint4*)(Bb + (size_t)(srow + 64) * K + 32);
    }
    __syncthreads();

    for (int kc = 0; kc < NC; ++kc) {
        int cur = kc & 1;
        if (kc + 1 < NC) {
            int nx = cur ^ 1;
            *(uint4*)&As[nx][sk8][srow][0]      = ra0;
            *(uint4*)&As[nx][sk8][srow + 64][0] = ra1;
            *(uint4*)&Bs[nx][sk8][srow][0]      = rb0;
            *(uint4*)&Bs[nx][sk8][srow + 64][0] = rb1;
        }
        if (kc + 2 < NC) {
            int kb = (kc + 2) << 5;
            ra0 = *(const uint4*)(Ab + (size_t)srow * K + kb);
            ra1 = *(const uint4*)(Ab + (size_t)(srow + 64) * K + kb);
            rb0 = *(const uint4*)(Bb + (size_t)srow * K + kb);
            rb1 = *(const uint4*)(Bb + (size_t)(srow + 64) * K + kb);
        }
        half8 af[2];
#pragma unroll
        for (int mg = 0; mg < 2; ++mg)
            af[mg] = *(const half8*)&As[cur][fk][(wv << 5) + (mg << 4) + fr][0];
#pragma unroll
        for (int ng = 0; ng < 8; ++ng) {
            half8 bf = *(const half8*)&Bs[cur][fk][(ng << 4) + fr][0];
            acc[0][ng] = __builtin_amdgcn_mfma_f32_16x16x32_f16(af[0], bf, acc[0][ng], 0, 0, 0);
            acc[1][ng] = __builtin_amdgcn_mfma_f32_16x16x32_f16(af[1], bf, acc[1][ng], 0, 0, 0);
        }
        __syncthreads();
    }
    int orow = m0 + (wv << 5) + (fk << 2);
#pragma unroll
    for (int mg = 0; mg < 2; ++mg)
#pragma unroll
        for (int ng = 0; ng < 8; ++ng)
#pragma unroll
            for (int i = 0; i < 4; ++i)
                C[(size_t)(orow + (mg << 4) + i) * N + n0 + (ng << 4) + fr] =
                    (_Float16)acc[mg][ng][i];
}

// -------------------------------------- weight transpose+convert: wT[n][k]=w[k][n]
__global__ __launch_bounds__(256) void wtrans_kernel(const float* __restrict__ w,
                                                     _Float16* __restrict__ wT,
                                                     int K, int N)
{
    int id = blockIdx.x * 256 + threadIdx.x;
    if (id >= K * N) return;
    int k = id / N, n = id - k * N;
    wT[(size_t)n * K + k] = (_Float16)w[id];
}

// --------------------------------------------------- BN stats (f32 input)
__global__ __launch_bounds__(256) void stats_part_kernel(const float* __restrict__ X,
                                                         int C,
                                                         float* __restrict__ ps,
                                                         float* __restrict__ pq)
{
    __shared__ float sl[256][4];
    __shared__ float ql[256][4];
    int t = threadIdx.x;
    int c = (blockIdx.x << 6) + ((t & 15) << 2);
    int rowsPer = 16384 / STAT_NCH;
    int r0 = blockIdx.y * rowsPer + (t >> 4);
    int rEnd = blockIdx.y * rowsPer + rowsPer;
    float4 s = {0.f, 0.f, 0.f, 0.f}, q = {0.f, 0.f, 0.f, 0.f};
    for (int r = r0; r < rEnd; r += 16) {
        float4 v = *(const float4*)(X + (size_t)r * C + c);
        s.x += v.x; s.y += v.y; s.z += v.z; s.w += v.w;
        q.x = fmaf(v.x, v.x, q.x); q.y = fmaf(v.y, v.y, q.y);
        q.z = fmaf(v.z, v.z, q.z); q.w = fmaf(v.w, v.w, q.w);
    }
    sl[t][0] = s.x; sl[t][1] = s.y; sl[t][2] = s.z; sl[t][3] = s.w;
    ql[t][0] = q.x; ql[t][1] = q.y; ql[t][2] = q.z; ql[t][3] = q.w;
    __syncthreads();
    if (t < 64) {
        int comp = t & 3, grp = t >> 2;
        float ss = 0.f, qq = 0.f;
#pragma unroll
        for (int g = 0; g < 16; ++g) {
            ss += sl[grp + (g << 4)][comp];
            qq += ql[grp + (g << 4)][comp];
        }
        ps[(size_t)blockIdx.y * C + (blockIdx.x << 6) + t] = ss;
        pq[(size_t)blockIdx.y * C + (blockIdx.x << 6) + t] = qq;
    }
}

// --------------------------------------------------- BN stats (f16 input)
__global__ __launch_bounds__(256) void stats_part_h_kernel(const _Float16* __restrict__ X,
                                                           int C,
                                                           float* __restrict__ ps,
                                                           float* __restrict__ pq)
{
    __shared__ float sl[256][4];
    __shared__ float ql[256][4];
    int t = threadIdx.x;
    int c = (blockIdx.x << 6) + ((t & 15) << 2);
    int rowsPer = 16384 / STAT_NCH;
    int r0 = blockIdx.y * rowsPer + (t >> 4);
    int rEnd = blockIdx.y * rowsPer + rowsPer;
    float4 s = {0.f, 0.f, 0.f, 0.f}, q = {0.f, 0.f, 0.f, 0.f};
    for (int r = r0; r < rEnd; r += 16) {
        half4v hv = *(const half4v*)(X + (size_t)r * C + c);
        float v0 = (float)hv[0], v1 = (float)hv[1], v2 = (float)hv[2], v3 = (float)hv[3];
        s.x += v0; s.y += v1; s.z += v2; s.w += v3;
        q.x = fmaf(v0, v0, q.x); q.y = fmaf(v1, v1, q.y);
        q.z = fmaf(v2, v2, q.z); q.w = fmaf(v3, v3, q.w);
    }
    sl[t][0] = s.x; sl[t][1] = s.y; sl[t][2] = s.z; sl[t][3] = s.w;
    ql[t][0] = q.x; ql[t][1] = q.y; ql[t][2] = q.z; ql[t][3] = q.w;
    __syncthreads();
    if (t < 64) {
        int comp = t & 3, grp = t >> 2;
        float ss = 0.f, qq = 0.f;
#pragma unroll
        for (int g = 0; g < 16; ++g) {
            ss += sl[grp + (g << 4)][comp];
            qq += ql[grp + (g << 4)][comp];
        }
        ps[(size_t)blockIdx.y * C + (blockIdx.x << 6) + t] = ss;
        pq[(size_t)blockIdx.y * C + (blockIdx.x << 6) + t] = qq;
    }
}

__global__ __launch_bounds__(64) void stats_fin_kernel(const float* __restrict__ ps,
                                                       const float* __restrict__ pq,
                                                       int C, float invM,
                                                       const float* __restrict__ g,
                                                       const float* __restrict__ bb,
                                                       float* __restrict__ scale,
                                                       float* __restrict__ shift)
{
    int c = blockIdx.x * 64 + threadIdx.x;
    float s = 0.f, q = 0.f;
    for (int ch = 0; ch < STAT_NCH; ++ch) { s += ps[(size_t)ch * C + c]; q += pq[(size_t)ch * C + c]; }
    float m  = s * invM;
    float v  = fmaxf(q * invM - m * m, 0.f);
    float sc = g[c] / sqrtf(v + EPSBN);
    scale[c] = sc;
    shift[c] = bb[c] - m * sc;
}

// ------------------------------------------- in-place BN+ReLU for C=64 layers
__global__ __launch_bounds__(256) void bn_relu64_kernel(float* __restrict__ X,
                                                        const float* __restrict__ scale,
                                                        const float* __restrict__ shift)
{
    int i = (blockIdx.x * 256 + threadIdx.x) * 4;
    float4 v = *(float4*)(X + i);
    int c = i & 63;
    v.x = fmaxf(fmaf(v.x, scale[c + 0], shift[c + 0]), 0.f);
    v.y = fmaxf(fmaf(v.y, scale[c + 1], shift[c + 1]), 0.f);
    v.z = fmaxf(fmaf(v.z, scale[c + 2], shift[c + 2]), 0.f);
    v.w = fmaxf(fmaf(v.w, scale[c + 3], shift[c + 3]), 0.f);
    *(float4*)(X + i) = v;
}

// ---------------------------------------- gather+max+relu C=64 -> f16 output
__global__ __launch_bounds__(256) void gmax1_kernel(const float* __restrict__ f,
                                                    const int* __restrict__ idx,
                                                    _Float16* __restrict__ agg)
{
    int t = threadIdx.x;
    int p = blockIdx.x * 4 + (t >> 6);
    int c = t & 63;
    int b = p >> 11;
    const int* ir = idx + (size_t)p * 16;
    const float* fb = f + ((size_t)(b << 11)) * 64;
    float m = -INFINITY;
#pragma unroll
    for (int k = 0; k < 16; ++k) {
        int nj = ir[k];
        m = fmaxf(m, fb[(size_t)nj * 64 + c]);
    }
    agg[(size_t)p * 64 + c] = (_Float16)fmaxf(m, 0.f);
}

// ------------- gather(f16) + bn on the fly + max + relu, C=512 -> f16 output
__global__ __launch_bounds__(256) void gmax2_kernel(const _Float16* __restrict__ f,
                                                    const float* __restrict__ scale,
                                                    const float* __restrict__ shift,
                                                    const int* __restrict__ idx,
                                                    _Float16* __restrict__ agg)
{
    int t = threadIdx.x;
    int p = blockIdx.x;
    int b = p >> 11;
    int c0 = t, c1 = t + 256;
    float s0 = scale[c0], h0 = shift[c0], s1 = scale[c1], h1 = shift[c1];
    const int* ir = idx + (size_t)p * 16;
    const _Float16* fb = f + ((size_t)(b << 11)) * 512;
    float m0 = -INFINITY, m1 = -INFINITY;
#pragma unroll
    for (int k = 0; k < 16; ++k) {
        int nj = ir[k];
        const _Float16* row = fb + (size_t)nj * 512;
        m0 = fmaxf(m0, fmaf((float)row[c0], s0, h0));
        m1 = fmaxf(m1, fmaf((float)row[c1], s1, h1));
    }
    _Float16* o = agg + (size_t)p * 512;
    o[c0] = (_Float16)fmaxf(m0, 0.f);
    o[c1] = (_Float16)fmaxf(m1, 0.f);
}

// ---------------- global max over N with bn applied (C=1024, f16 input)
__global__ __launch_bounds__(256) void globpart_kernel(const _Float16* __restrict__ f,
                                                       const float* __restrict__ scale,
                                                       const float* __restrict__ shift,
                                                       float* __restrict__ part)
{
    int c = blockIdx.x * 256 + threadIdx.x;
    int b = blockIdx.z, ch = blockIdx.y;
    float sc = scale[c], sh = shift[c];
    const _Float16* fb = f + ((size_t)(b << 11) + ch * 256) * 1024;
    float m = -INFINITY;
    for (int n = 0; n < 256; ++n)
        m = fmaxf(m, fmaf((float)fb[(size_t)n * 1024 + c], sc, sh));
    part[((size_t)(b * 8 + ch)) * 1024 + c] = m;
}

__global__ __launch_bounds__(256) void globred_kernel(const float* __restrict__ part,
                                                      float* __restrict__ glob)
{
    int c = blockIdx.x * 256 + threadIdx.x;
    int b = blockIdx.y;
    float m = -INFINITY;
#pragma unroll
    for (int ch = 0; ch < 8; ++ch)
        m = fmaxf(m, part[((size_t)(b * 8 + ch)) * 1024 + c]);
    glob[(size_t)b * 1024 + c] = m;
}

// ---------------------------------------- final (8x1024)@(1024x512) + BN(8)
__global__ __launch_bounds__(256) void final_kernel(const float* __restrict__ glob,
                                                    const float* __restrict__ w2,
                                                    const float* __restrict__ g,
                                                    const float* __restrict__ bb,
                                                    float* __restrict__ out)
{
    __shared__ float vals[8][64];
    int t  = threadIdx.x;
    int c0 = blockIdx.x * 64;
    int r  = t >> 5, cl = t & 31;
    const float* gr = glob + (size_t)r * 1024;
    float a0 = 0.f, a1 = 0.f;
    int ca = c0 + cl, cb = c0 + cl + 32;
    for (int k = 0; k < 1024; ++k) {
        float gv = gr[k];
        a0 = fmaf(gv, w2[(size_t)k * 512 + ca], a0);
        a1 = fmaf(gv, w2[(size_t)k * 512 + cb], a1);
    }
    vals[r][cl] = a0; vals[r][cl + 32] = a1;
    __syncthreads();
    if (t < 64) {
        int c = c0 + t;
        float s = 0.f;
#pragma unroll
        for (int rr = 0; rr < 8; ++rr) s += vals[rr][t];
        float m = s * 0.125f;
        float v = 0.f;
#pragma unroll
        for (int rr = 0; rr < 8; ++rr) { float d = vals[rr][t] - m; v = fmaf(d, d, v); }
        v *= 0.125f;
        float sc = g[c] / sqrtf(v + EPSBN);
#pragma unroll
        for (int rr = 0; rr < 8; ++rr)
            out[(size_t)rr * 512 + c] = fmaf(vals[rr][t] - m, sc, bb[c]);
    }
}

// =============================================================== launch
extern "C" void kernel_launch(void* const* d_in, const int* in_sizes, int n_in,
                              void* d_out, int out_size, void* d_ws, size_t ws_size,
                              hipStream_t stream)
{
    const float* x   = (const float*)d_in[0];
    const float* w1a = (const float*)d_in[1];
    const float* g1a = (const float*)d_in[2];
    const float* b1a = (const float*)d_in[3];
    const float* w1b = (const float*)d_in[4];
    const float* g1b = (const float*)d_in[5];
    const float* b1b = (const float*)d_in[6];
    const float* w1c = (const float*)d_in[7];
    const float* g1c = (const float*)d_in[8];
    const float* b1c = (const float*)d_in[9];
    const float* wg1 = (const float*)d_in[10];
    const float* gg1 = (const float*)d_in[11];
    const float* bg1 = (const float*)d_in[12];
    const float* wg2 = (const float*)d_in[13];
    const float* gg2 = (const float*)d_in[14];
    const float* bg2 = (const float*)d_in[15];
    const float* w2  = (const float*)d_in[16];
    const float* g2  = (const float*)d_in[17];
    const float* b2  = (const float*)d_in[18];

    char* w = (char*)d_ws;
    size_t off = 0;
    auto take = [&](size_t bytes) -> char* {
        char* p = w + off;
        off += (bytes + 255) & ~(size_t)255;
        return p;
    };
    int*       idx     = (int*)      take((size_t)16384 * 16 * 4);
    float*     f19     = (float*)    take((size_t)16384 * 19 * 4);
    float*     hA      = (float*)    take((size_t)16384 * 64 * 4);
    float*     hB      = (float*)    take((size_t)16384 * 64 * 4);
    _Float16*  f512h   = (_Float16*) take((size_t)16384 * 512 * 2);
    _Float16*  f1024h  = (_Float16*) take((size_t)16384 * 1024 * 2);
    _Float16*  aggh64  = (_Float16*) take((size_t)16384 * 64 * 2);
    _Float16*  agg512h = (_Float16*) take((size_t)16384 * 512 * 2);
    _Float16*  w1T     = (_Float16*) take((size_t)512 * 64 * 2);
    _Float16*  w2T     = (_Float16*) take((size_t)1024 * 512 * 2);
    float*     ps      = (float*)    take((size_t)STAT_NCH * 1024 * 4);
    float*     pq      = (float*)    take((size_t)STAT_NCH * 1024 * 4);
    float* scA  = (float*)take(64 * 4);   float* shA  = (float*)take(64 * 4);
    float* scB  = (float*)take(64 * 4);   float* shB  = (float*)take(64 * 4);
    float* scC  = (float*)take(64 * 4);   float* shC  = (float*)take(64 * 4);
    float* scG1 = (float*)take(512 * 4);  float* shG1 = (float*)take(512 * 4);
    float* scG2 = (float*)take(1024 * 4); float* shG2 = (float*)take(1024 * 4);
    float* part = (float*)take((size_t)8 * 8 * 1024 * 4);
    float* glob = (float*)take((size_t)8 * 1024 * 4);
    (void)ws_size; (void)in_sizes; (void)n_in; (void)out_size;

    const float invM = 1.0f / 16384.0f;

    // weight conversions (depend only on inputs) + knn up front
    wtrans_kernel<<<(64 * 512 + 255) / 256, 256, 0, stream>>>(wg1, w1T, 64, 512);
    wtrans_kernel<<<(512 * 1024 + 255) / 256, 256, 0, stream>>>(wg2, w2T, 512, 1024);
    knn_kernel<<<256, 1024, 0, stream>>>(x, idx);
    cov_feat_kernel<<<64, 256, 0, stream>>>(x, idx, f19);

    // L1a: 19 -> 64
    lin19_kernel<<<4096, 256, 0, stream>>>(f19, w1a, hA);
    stats_part_kernel<<<dim3(1, STAT_NCH), 256, 0, stream>>>(hA, 64, ps, pq);
    stats_fin_kernel<<<1, 64, 0, stream>>>(ps, pq, 64, invM, g1a, b1a, scA, shA);
    bn_relu64_kernel<<<1024, 256, 0, stream>>>(hA, scA, shA);

    // L1b: 64 -> 64
    gemm_kernel<<<dim3(1, 256), 256, 0, stream>>>(hA, w1b, hB, 16384, 64, 64);
    stats_part_kernel<<<dim3(1, STAT_NCH), 256, 0, stream>>>(hB, 64, ps, pq);
    stats_fin_kernel<<<1, 64, 0, stream>>>(ps, pq, 64, invM, g1b, b1b, scB, shB);
    bn_relu64_kernel<<<1024, 256, 0, stream>>>(hB, scB, shB);

    // L1c: 64 -> 64
    gemm_kernel<<<dim3(1, 256), 256, 0, stream>>>(hB, w1c, hA, 16384, 64, 64);
    stats_part_kernel<<<dim3(1, STAT_NCH), 256, 0, stream>>>(hA, 64, ps, pq);
    stats_fin_kernel<<<1, 64, 0, stream>>>(ps, pq, 64, invM, g1c, b1c, scC, shC);
    bn_relu64_kernel<<<1024, 256, 0, stream>>>(hA, scC, shC);

    // graph pool 1: gather-max-relu(f16) then f16 MFMA 64->512 GEMM (f16 out)
    gmax1_kernel<<<4096, 256, 0, stream>>>(hA, idx, aggh64);
    hgemm_kernel<<<dim3(4, 128), 256, 0, stream>>>(aggh64, w1T, f512h, 16384, 512, 64);
    stats_part_h_kernel<<<dim3(8, STAT_NCH), 256, 0, stream>>>(f512h, 512, ps, pq);
    stats_fin_kernel<<<8, 64, 0, stream>>>(ps, pq, 512, invM, gg1, bg1, scG1, shG1);

    // graph pool 2: gather(bn)-max-relu(f16) then f16 MFMA 512->1024 GEMM (f16 out)
    gmax2_kernel<<<16384, 256, 0, stream>>>(f512h, scG1, shG1, idx, agg512h);
    hgemm_kernel<<<dim3(8, 128), 256, 0, stream>>>(agg512h, w2T, f1024h, 16384, 1024, 512);
    stats_part_h_kernel<<<dim3(16, STAT_NCH), 256, 0, stream>>>(f1024h, 1024, ps, pq);
    stats_fin_kernel<<<16, 64, 0, stream>>>(ps, pq, 1024, invM, gg2, bg2, scG2, shG2);

    // global max over N with bn applied on the fly
    globpart_kernel<<<dim3(4, 8, 8), 256, 0, stream>>>(f1024h, scG2, shG2, part);
    globred_kernel<<<dim3(4, 8), 256, 0, stream>>>(part, glob);

    // final linear + BN over 8 rows
    final_kernel<<<8, 256, 0, stream>>>(glob, w2, g2, b2, (float*)d_out);
}

// Round 8
// 420.094 us; speedup vs baseline: 1.3631x; 1.0365x over previous
//
#include <hip/hip_runtime.h>
#include <math.h>

#define EPSBN 1e-5f
#define STAT_NCH 128

typedef _Float16 half8 __attribute__((ext_vector_type(8)));
typedef _Float16 half4v __attribute__((ext_vector_type(4)));
typedef float floatx4 __attribute__((ext_vector_type(4)));

// ---------------------------------- KNN (top-16), 512 blocks x 256 thr
// 32 queries/block, 8 chunks of 256 candidates. LDS ~50 KB -> 3 blocks/CU,
// no VGPR cap (256-thr default) so the 88-VGPR fast inner loop is preserved.
__global__ __launch_bounds__(256) void knn_kernel(const float* __restrict__ x,
                                                  int* __restrict__ idx)
{
    __shared__ float  xs[2048], ys[2048], sq[2048];   // 24 KB
    __shared__ float  md[8][32][17];                  // 17 KB, odd stride
    __shared__ ushort mi[8][32][18];                  // 9 KB, odd stride
    int b  = blockIdx.x >> 6;              // 64 blocks per batch
    int q0 = (blockIdx.x & 63) << 5;       // 32 queries per block
    const float* xb = x + (size_t)b * 2048 * 10;
    for (int j = threadIdx.x; j < 2048; j += 256) {
        float xj = xb[j * 10 + 0], yj = xb[j * 10 + 1];
        xs[j] = xj; ys[j] = yj;
        sq[j] = __fadd_rn(__fmul_rn(xj, xj), __fmul_rn(yj, yj));
    }
    __syncthreads();
    int qq    = threadIdx.x & 31;          // query within block
    int chunk = threadIdx.x >> 5;          // 0..7
    int i = q0 + qq;                       // query index within batch
    float xi = xs[i], yi = ys[i], sqi = sq[i];
    float bd[16]; int bi[16];
#pragma unroll
    for (int s = 0; s < 16; ++s) { bd[s] = INFINITY; bi[s] = 0; }
    int j0 = chunk << 8;                   // 256 candidates per chunk
    for (int jj = 0; jj < 256; ++jj) {
        int j = j0 + jj;
        float dot = __fadd_rn(__fmul_rn(xi, xs[j]), __fmul_rn(yi, ys[j]));
        float d   = __fsub_rn(__fadd_rn(sqi, sq[j]), __fmul_rn(2.0f, dot));
        if (j == i) d = INFINITY;
        if (d < bd[15]) {                  // strict < : ties keep lower index
            bd[15] = d; bi[15] = j;
#pragma unroll
            for (int s = 15; s > 0; --s) {
                if (bd[s] < bd[s - 1]) {
                    float td = bd[s]; bd[s] = bd[s - 1]; bd[s - 1] = td;
                    int   ti = bi[s]; bi[s] = bi[s - 1]; bi[s - 1] = ti;
                }
            }
        }
    }
#pragma unroll
    for (int s = 0; s < 16; ++s) { md[chunk][qq][s] = bd[s]; mi[chunk][qq][s] = (ushort)bi[s]; }
    __syncthreads();
    if (threadIdx.x < 32) {
        int q = threadIdx.x;
        float fd[16]; int fi[16];
#pragma unroll
        for (int s = 0; s < 16; ++s) { fd[s] = INFINITY; fi[s] = 0; }
        for (int c = 0; c < 8; ++c) {
            for (int s = 0; s < 16; ++s) {
                float d = md[c][q][s];
                if (!(d < fd[15])) break;  // sorted list: rest can't qualify
                int j = (int)mi[c][q][s];
                fd[15] = d; fi[15] = j;
#pragma unroll
                for (int t = 15; t > 0; --t) {
                    if (fd[t] < fd[t - 1]) {
                        float td = fd[t]; fd[t] = fd[t - 1]; fd[t - 1] = td;
                        int   ti = fi[t]; fi[t] = fi[t - 1]; fi[t - 1] = ti;
                    }
                }
            }
        }
        int* out = idx + (size_t)(b * 2048 + q0 + q) * 16;
#pragma unroll
        for (int s = 0; s < 16; ++s) out[s] = fi[s];
    }
}

// ------------------------------------------------- covariance + 19-ch feature
__global__ __launch_bounds__(256) void cov_feat_kernel(const float* __restrict__ x,
                                                       const int* __restrict__ idx,
                                                       float* __restrict__ f19)
{
    int p = blockIdx.x * 256 + threadIdx.x;   // 0..16383
    int b = p >> 11;
    const float* xr = x + (size_t)p * 10;
    float v0 = xr[0], v1 = xr[1], v2 = xr[2], v3 = xr[3], v4 = xr[4];
    float v5 = xr[5], v6 = xr[6], v7 = xr[7], v8 = xr[8], v9 = xr[9];
    float e = v2 + v3 + v4 + v5 + v6 + v7 + v8 + v9;
    float sx = v0, sy = v1, se = e;
    float sxx = v0 * v0, sxy = v0 * v1, sxe = v0 * e;
    float syy = v1 * v1, sye = v1 * e, see = e * e;
    const int* ir = idx + (size_t)p * 16;
    const float* xb = x + ((size_t)(b << 11)) * 10;
#pragma unroll
    for (int k = 0; k < 16; ++k) {
        int nj = ir[k];
        const float* nr = xb + (size_t)nj * 10;
        float nx = nr[0], ny = nr[1];
        float ne = nr[2] + nr[3] + nr[4] + nr[5] + nr[6] + nr[7] + nr[8] + nr[9];
        sx += nx; sy += ny; se += ne;
        sxx += nx * nx; sxy += nx * ny; sxe += nx * ne;
        syy += ny * ny; sye += ny * ne; see += ne * ne;
    }
    const float inv = 1.0f / 17.0f;
    float mx = sx * inv, my = sy * inv, me = se * inv;
    float cxx = sxx * inv - mx * mx, cxy = sxy * inv - mx * my, cxe = sxe * inv - mx * me;
    float cyy = syy * inv - my * my, cye = sye * inv - my * me, cee = see * inv - me * me;
    float* o = f19 + (size_t)p * 19;
    o[0] = v0; o[1] = v1; o[2] = v2; o[3] = v3; o[4] = v4;
    o[5] = v5; o[6] = v6; o[7] = v7; o[8] = v8; o[9] = v9;
    o[10] = cxx; o[11] = cxy; o[12] = cxe;
    o[13] = cxy; o[14] = cyy; o[15] = cye;
    o[16] = cxe; o[17] = cye; o[18] = cee;
}

// ------------------------------------------------------------- 19->64 GEMM
__global__ __launch_bounds__(256) void lin19_kernel(const float* __restrict__ f19,
                                                    const float* __restrict__ w,
                                                    float* __restrict__ out)
{
    __shared__ float ws_[19 * 64];
    __shared__ float fr[4 * 19];
    int t = threadIdx.x;
    for (int i = t; i < 19 * 64; i += 256) ws_[i] = w[i];
    int p0 = blockIdx.x * 4;
    for (int i = t; i < 4 * 19; i += 256) fr[i] = f19[(size_t)p0 * 19 + i];
    __syncthreads();
    int lp = t >> 6, c = t & 63;
    float acc = 0.f;
#pragma unroll
    for (int k = 0; k < 19; ++k) acc = fmaf(fr[lp * 19 + k], ws_[k * 64 + c], acc);
    out[(size_t)(p0 + lp) * 64 + c] = acc;
}

// ---------------------------------------------------- generic fp32 tiled GEMM
__global__ __launch_bounds__(256) void gemm_kernel(const float* __restrict__ A,
                                                   const float* __restrict__ B,
                                                   float* __restrict__ C,
                                                   int M, int N, int K)
{
    __shared__ float As[16][64];   // [k][row]
    __shared__ float Bs[16][64];   // [k][col]
    int t  = threadIdx.x;
    int m0 = blockIdx.y << 6, n0 = blockIdx.x << 6;
    int arow = t >> 2, acol = (t & 3) << 2;
    int brow = t >> 4, bcol = (t & 15) << 2;
    int tr = (t >> 4) << 2, tc = (t & 15) << 2;
    float acc[4][4] = {};
    for (int k0 = 0; k0 < K; k0 += 16) {
        float4 av = *(const float4*)(A + (size_t)(m0 + arow) * K + k0 + acol);
        float4 bv = *(const float4*)(B + (size_t)(k0 + brow) * N + n0 + bcol);
        __syncthreads();
        As[acol + 0][arow] = av.x; As[acol + 1][arow] = av.y;
        As[acol + 2][arow] = av.z; As[acol + 3][arow] = av.w;
        *(float4*)&Bs[brow][bcol] = bv;
        __syncthreads();
#pragma unroll
        for (int kk = 0; kk < 16; ++kk) {
            float4 a = *(const float4*)&As[kk][tr];
            float4 bb = *(const float4*)&Bs[kk][tc];
            float ar[4] = {a.x, a.y, a.z, a.w};
            float br[4] = {bb.x, bb.y, bb.z, bb.w};
#pragma unroll
            for (int i = 0; i < 4; ++i)
#pragma unroll
                for (int j = 0; j < 4; ++j)
                    acc[i][j] = fmaf(ar[i], br[j], acc[i][j]);
        }
    }
#pragma unroll
    for (int i = 0; i < 4; ++i) {
        float4 o;
        o.x = acc[i][0]; o.y = acc[i][1]; o.z = acc[i][2]; o.w = acc[i][3];
        *(float4*)(C + (size_t)(m0 + tr + i) * N + n0 + tc) = o;
    }
}

// ---------------------------------------------- fp16 MFMA GEMM, 128x128 tile
// A [M][K] f16 row-major, BT [N][K] f16 row-major, C [M][N] f16. K%32==0.
__global__ __launch_bounds__(256) void hgemm_kernel(const _Float16* __restrict__ A,
                                                    const _Float16* __restrict__ BT,
                                                    _Float16* __restrict__ C,
                                                    int M, int N, int K)
{
    __shared__ __align__(16) _Float16 As[2][4][128][8];
    __shared__ __align__(16) _Float16 Bs[2][4][128][8];
    int t = threadIdx.x;
    int m0 = blockIdx.y << 7, n0 = blockIdx.x << 7;
    int wv = t >> 6, lane = t & 63;
    int fr = lane & 15, fk = lane >> 4;
    int srow = t & 63, sk8 = t >> 6;
    const _Float16* Ab = A + (size_t)m0 * K + sk8 * 8;
    const _Float16* Bb = BT + (size_t)n0 * K + sk8 * 8;

    floatx4 zero = {0.f, 0.f, 0.f, 0.f};
    floatx4 acc[2][8];
#pragma unroll
    for (int i = 0; i < 2; ++i)
#pragma unroll
        for (int j = 0; j < 8; ++j) acc[i][j] = zero;

    int NC = K >> 5;
    {
        uint4 a0 = *(const uint4*)(Ab + (size_t)srow * K);
        uint4 a1 = *(const uint4*)(Ab + (size_t)(srow + 64) * K);
        uint4 b0 = *(const uint4*)(Bb + (size_t)srow * K);
        uint4 b1 = *(const uint4*)(Bb + (size_t)(srow + 64) * K);
        *(uint4*)&As[0][sk8][srow][0]      = a0;
        *(uint4*)&As[0][sk8][srow + 64][0] = a1;
        *(uint4*)&Bs[0][sk8][srow][0]      = b0;
        *(uint4*)&Bs[0][sk8][srow + 64][0] = b1;
    }
    uint4 ra0, ra1, rb0, rb1;
    if (NC > 1) {
        ra0 = *(const uint4*)(Ab + (size_t)srow * K + 32);
        ra1 = *(const uint4*)(Ab + (size_t)(srow + 64) * K + 32);
        rb0 = *(const uint4*)(Bb + (size_t)srow * K + 32);
        rb1 = *(const uint4*)(Bb + (size_t)(srow + 64) * K + 32);
    }
    __syncthreads();

    for (int kc = 0; kc < NC; ++kc) {
        int cur = kc & 1;
        if (kc + 1 < NC) {
            int nx = cur ^ 1;
            *(uint4*)&As[nx][sk8][srow][0]      = ra0;
            *(uint4*)&As[nx][sk8][srow + 64][0] = ra1;
            *(uint4*)&Bs[nx][sk8][srow][0]      = rb0;
            *(uint4*)&Bs[nx][sk8][srow + 64][0] = rb1;
        }
        if (kc + 2 < NC) {
            int kb = (kc + 2) << 5;
            ra0 = *(const uint4*)(Ab + (size_t)srow * K + kb);
            ra1 = *(const uint4*)(Ab + (size_t)(srow + 64) * K + kb);
            rb0 = *(const uint4*)(Bb + (size_t)srow * K + kb);
            rb1 = *(const uint4*)(Bb + (size_t)(srow + 64) * K + kb);
        }
        half8 af[2];
#pragma unroll
        for (int mg = 0; mg < 2; ++mg)
            af[mg] = *(const half8*)&As[cur][fk][(wv << 5) + (mg << 4) + fr][0];
#pragma unroll
        for (int ng = 0; ng < 8; ++ng) {
            half8 bf = *(const half8*)&Bs[cur][fk][(ng << 4) + fr][0];
            acc[0][ng] = __builtin_amdgcn_mfma_f32_16x16x32_f16(af[0], bf, acc[0][ng], 0, 0, 0);
            acc[1][ng] = __builtin_amdgcn_mfma_f32_16x16x32_f16(af[1], bf, acc[1][ng], 0, 0, 0);
        }
        __syncthreads();
    }
    int orow = m0 + (wv << 5) + (fk << 2);
#pragma unroll
    for (int mg = 0; mg < 2; ++mg)
#pragma unroll
        for (int ng = 0; ng < 8; ++ng)
#pragma unroll
            for (int i = 0; i < 4; ++i)
                C[(size_t)(orow + (mg << 4) + i) * N + n0 + (ng << 4) + fr] =
                    (_Float16)acc[mg][ng][i];
}

// -------------------------------------- weight transpose+convert: wT[n][k]=w[k][n]
__global__ __launch_bounds__(256) void wtrans_kernel(const float* __restrict__ w,
                                                     _Float16* __restrict__ wT,
                                                     int K, int N)
{
    int id = blockIdx.x * 256 + threadIdx.x;
    if (id >= K * N) return;
    int k = id / N, n = id - k * N;
    wT[(size_t)n * K + k] = (_Float16)w[id];
}

// --------------------------------------------------- BN stats (f32 input)
__global__ __launch_bounds__(256) void stats_part_kernel(const float* __restrict__ X,
                                                         int C,
                                                         float* __restrict__ ps,
                                                         float* __restrict__ pq)
{
    __shared__ float sl[256][4];
    __shared__ float ql[256][4];
    int t = threadIdx.x;
    int c = (blockIdx.x << 6) + ((t & 15) << 2);
    int rowsPer = 16384 / STAT_NCH;
    int r0 = blockIdx.y * rowsPer + (t >> 4);
    int rEnd = blockIdx.y * rowsPer + rowsPer;
    float4 s = {0.f, 0.f, 0.f, 0.f}, q = {0.f, 0.f, 0.f, 0.f};
    for (int r = r0; r < rEnd; r += 16) {
        float4 v = *(const float4*)(X + (size_t)r * C + c);
        s.x += v.x; s.y += v.y; s.z += v.z; s.w += v.w;
        q.x = fmaf(v.x, v.x, q.x); q.y = fmaf(v.y, v.y, q.y);
        q.z = fmaf(v.z, v.z, q.z); q.w = fmaf(v.w, v.w, q.w);
    }
    sl[t][0] = s.x; sl[t][1] = s.y; sl[t][2] = s.z; sl[t][3] = s.w;
    ql[t][0] = q.x; ql[t][1] = q.y; ql[t][2] = q.z; ql[t][3] = q.w;
    __syncthreads();
    if (t < 64) {
        int comp = t & 3, grp = t >> 2;
        float ss = 0.f, qq = 0.f;
#pragma unroll
        for (int g = 0; g < 16; ++g) {
            ss += sl[grp + (g << 4)][comp];
            qq += ql[grp + (g << 4)][comp];
        }
        ps[(size_t)blockIdx.y * C + (blockIdx.x << 6) + t] = ss;
        pq[(size_t)blockIdx.y * C + (blockIdx.x << 6) + t] = qq;
    }
}

// --------------------------------------------------- BN stats (f16 input)
__global__ __launch_bounds__(256) void stats_part_h_kernel(const _Float16* __restrict__ X,
                                                           int C,
                                                           float* __restrict__ ps,
                                                           float* __restrict__ pq)
{
    __shared__ float sl[256][4];
    __shared__ float ql[256][4];
    int t = threadIdx.x;
    int c = (blockIdx.x << 6) + ((t & 15) << 2);
    int rowsPer = 16384 / STAT_NCH;
    int r0 = blockIdx.y * rowsPer + (t >> 4);
    int rEnd = blockIdx.y * rowsPer + rowsPer;
    float4 s = {0.f, 0.f, 0.f, 0.f}, q = {0.f, 0.f, 0.f, 0.f};
    for (int r = r0; r < rEnd; r += 16) {
        half4v hv = *(const half4v*)(X + (size_t)r * C + c);
        float v0 = (float)hv[0], v1 = (float)hv[1], v2 = (float)hv[2], v3 = (float)hv[3];
        s.x += v0; s.y += v1; s.z += v2; s.w += v3;
        q.x = fmaf(v0, v0, q.x); q.y = fmaf(v1, v1, q.y);
        q.z = fmaf(v2, v2, q.z); q.w = fmaf(v3, v3, q.w);
    }
    sl[t][0] = s.x; sl[t][1] = s.y; sl[t][2] = s.z; sl[t][3] = s.w;
    ql[t][0] = q.x; ql[t][1] = q.y; ql[t][2] = q.z; ql[t][3] = q.w;
    __syncthreads();
    if (t < 64) {
        int comp = t & 3, grp = t >> 2;
        float ss = 0.f, qq = 0.f;
#pragma unroll
        for (int g = 0; g < 16; ++g) {
            ss += sl[grp + (g << 4)][comp];
            qq += ql[grp + (g << 4)][comp];
        }
        ps[(size_t)blockIdx.y * C + (blockIdx.x << 6) + t] = ss;
        pq[(size_t)blockIdx.y * C + (blockIdx.x << 6) + t] = qq;
    }
}

__global__ __launch_bounds__(64) void stats_fin_kernel(const float* __restrict__ ps,
                                                       const float* __restrict__ pq,
                                                       int C, float invM,
                                                       const float* __restrict__ g,
                                                       const float* __restrict__ bb,
                                                       float* __restrict__ scale,
                                                       float* __restrict__ shift)
{
    int c = blockIdx.x * 64 + threadIdx.x;
    float s = 0.f, q = 0.f;
    for (int ch = 0; ch < STAT_NCH; ++ch) { s += ps[(size_t)ch * C + c]; q += pq[(size_t)ch * C + c]; }
    float m  = s * invM;
    float v  = fmaxf(q * invM - m * m, 0.f);
    float sc = g[c] / sqrtf(v + EPSBN);
    scale[c] = sc;
    shift[c] = bb[c] - m * sc;
}

// ------------------------------------------- in-place BN+ReLU for C=64 layers
__global__ __launch_bounds__(256) void bn_relu64_kernel(float* __restrict__ X,
                                                        const float* __restrict__ scale,
                                                        const float* __restrict__ shift)
{
    int i = (blockIdx.x * 256 + threadIdx.x) * 4;
    float4 v = *(float4*)(X + i);
    int c = i & 63;
    v.x = fmaxf(fmaf(v.x, scale[c + 0], shift[c + 0]), 0.f);
    v.y = fmaxf(fmaf(v.y, scale[c + 1], shift[c + 1]), 0.f);
    v.z = fmaxf(fmaf(v.z, scale[c + 2], shift[c + 2]), 0.f);
    v.w = fmaxf(fmaf(v.w, scale[c + 3], shift[c + 3]), 0.f);
    *(float4*)(X + i) = v;
}

// ---------------------------------------- gather+max+relu C=64 -> f16 output
__global__ __launch_bounds__(256) void gmax1_kernel(const float* __restrict__ f,
                                                    const int* __restrict__ idx,
                                                    _Float16* __restrict__ agg)
{
    int t = threadIdx.x;
    int p = blockIdx.x * 4 + (t >> 6);
    int c = t & 63;
    int b = p >> 11;
    const int* ir = idx + (size_t)p * 16;
    const float* fb = f + ((size_t)(b << 11)) * 64;
    float m = -INFINITY;
#pragma unroll
    for (int k = 0; k < 16; ++k) {
        int nj = ir[k];
        m = fmaxf(m, fb[(size_t)nj * 64 + c]);
    }
    agg[(size_t)p * 64 + c] = (_Float16)fmaxf(m, 0.f);
}

// ------------- gather(f16) + bn on the fly + max + relu, C=512 -> f16 output
__global__ __launch_bounds__(256) void gmax2_kernel(const _Float16* __restrict__ f,
                                                    const float* __restrict__ scale,
                                                    const float* __restrict__ shift,
                                                    const int* __restrict__ idx,
                                                    _Float16* __restrict__ agg)
{
    int t = threadIdx.x;
    int p = blockIdx.x;
    int b = p >> 11;
    int c0 = t, c1 = t + 256;
    float s0 = scale[c0], h0 = shift[c0], s1 = scale[c1], h1 = shift[c1];
    const int* ir = idx + (size_t)p * 16;
    const _Float16* fb = f + ((size_t)(b << 11)) * 512;
    float m0 = -INFINITY, m1 = -INFINITY;
#pragma unroll
    for (int k = 0; k < 16; ++k) {
        int nj = ir[k];
        const _Float16* row = fb + (size_t)nj * 512;
        m0 = fmaxf(m0, fmaf((float)row[c0], s0, h0));
        m1 = fmaxf(m1, fmaf((float)row[c1], s1, h1));
    }
    _Float16* o = agg + (size_t)p * 512;
    o[c0] = (_Float16)fmaxf(m0, 0.f);
    o[c1] = (_Float16)fmaxf(m1, 0.f);
}

// ---------------- global max over N with bn applied (C=1024, f16 input)
__global__ __launch_bounds__(256) void globpart_kernel(const _Float16* __restrict__ f,
                                                       const float* __restrict__ scale,
                                                       const float* __restrict__ shift,
                                                       float* __restrict__ part)
{
    int c = blockIdx.x * 256 + threadIdx.x;
    int b = blockIdx.z, ch = blockIdx.y;
    float sc = scale[c], sh = shift[c];
    const _Float16* fb = f + ((size_t)(b << 11) + ch * 256) * 1024;
    float m = -INFINITY;
    for (int n = 0; n < 256; ++n)
        m = fmaxf(m, fmaf((float)fb[(size_t)n * 1024 + c], sc, sh));
    part[((size_t)(b * 8 + ch)) * 1024 + c] = m;
}

__global__ __launch_bounds__(256) void globred_kernel(const float* __restrict__ part,
                                                      float* __restrict__ glob)
{
    int c = blockIdx.x * 256 + threadIdx.x;
    int b = blockIdx.y;
    float m = -INFINITY;
#pragma unroll
    for (int ch = 0; ch < 8; ++ch)
        m = fmaxf(m, part[((size_t)(b * 8 + ch)) * 1024 + c]);
    glob[(size_t)b * 1024 + c] = m;
}

// ---------------------------------------- final (8x1024)@(1024x512) + BN(8)
__global__ __launch_bounds__(256) void final_kernel(const float* __restrict__ glob,
                                                    const float* __restrict__ w2,
                                                    const float* __restrict__ g,
                                                    const float* __restrict__ bb,
                                                    float* __restrict__ out)
{
    __shared__ float vals[8][64];
    int t  = threadIdx.x;
    int c0 = blockIdx.x * 64;
    int r  = t >> 5, cl = t & 31;
    const float* gr = glob + (size_t)r * 1024;
    float a0 = 0.f, a1 = 0.f;
    int ca = c0 + cl, cb = c0 + cl + 32;
    for (int k = 0; k < 1024; ++k) {
        float gv = gr[k];
        a0 = fmaf(gv, w2[(size_t)k * 512 + ca], a0);
        a1 = fmaf(gv, w2[(size_t)k * 512 + cb], a1);
    }
    vals[r][cl] = a0; vals[r][cl + 32] = a1;
    __syncthreads();
    if (t < 64) {
        int c = c0 + t;
        float s = 0.f;
#pragma unroll
        for (int rr = 0; rr < 8; ++rr) s += vals[rr][t];
        float m = s * 0.125f;
        float v = 0.f;
#pragma unroll
        for (int rr = 0; rr < 8; ++rr) { float d = vals[rr][t] - m; v = fmaf(d, d, v); }
        v *= 0.125f;
        float sc = g[c] / sqrtf(v + EPSBN);
#pragma unroll
        for (int rr = 0; rr < 8; ++rr)
            out[(size_t)rr * 512 + c] = fmaf(vals[rr][t] - m, sc, bb[c]);
    }
}

// =============================================================== launch
extern "C" void kernel_launch(void* const* d_in, const int* in_sizes, int n_in,
                              void* d_out, int out_size, void* d_ws, size_t ws_size,
                              hipStream_t stream)
{
    const float* x   = (const float*)d_in[0];
    const float* w1a = (const float*)d_in[1];
    const float* g1a = (const float*)d_in[2];
    const float* b1a = (const float*)d_in[3];
    const float* w1b = (const float*)d_in[4];
    const float* g1b = (const float*)d_in[5];
    const float* b1b = (const float*)d_in[6];
    const float* w1c = (const float*)d_in[7];
    const float* g1c = (const float*)d_in[8];
    const float* b1c = (const float*)d_in[9];
    const float* wg1 = (const float*)d_in[10];
    const float* gg1 = (const float*)d_in[11];
    const float* bg1 = (const float*)d_in[12];
    const float* wg2 = (const float*)d_in[13];
    const float* gg2 = (const float*)d_in[14];
    const float* bg2 = (const float*)d_in[15];
    const float* w2  = (const float*)d_in[16];
    const float* g2  = (const float*)d_in[17];
    const float* b2  = (const float*)d_in[18];

    char* w = (char*)d_ws;
    size_t off = 0;
    auto take = [&](size_t bytes) -> char* {
        char* p = w + off;
        off += (bytes + 255) & ~(size_t)255;
        return p;
    };
    int*       idx     = (int*)      take((size_t)16384 * 16 * 4);
    float*     f19     = (float*)    take((size_t)16384 * 19 * 4);
    float*     hA      = (float*)    take((size_t)16384 * 64 * 4);
    float*     hB      = (float*)    take((size_t)16384 * 64 * 4);
    _Float16*  f512h   = (_Float16*) take((size_t)16384 * 512 * 2);
    _Float16*  f1024h  = (_Float16*) take((size_t)16384 * 1024 * 2);
    _Float16*  aggh64  = (_Float16*) take((size_t)16384 * 64 * 2);
    _Float16*  agg512h = (_Float16*) take((size_t)16384 * 512 * 2);
    _Float16*  w1T     = (_Float16*) take((size_t)512 * 64 * 2);
    _Float16*  w2T     = (_Float16*) take((size_t)1024 * 512 * 2);
    float*     ps      = (float*)    take((size_t)STAT_NCH * 1024 * 4);
    float*     pq      = (float*)    take((size_t)STAT_NCH * 1024 * 4);
    float* scA  = (float*)take(64 * 4);   float* shA  = (float*)take(64 * 4);
    float* scB  = (float*)take(64 * 4);   float* shB  = (float*)take(64 * 4);
    float* scC  = (float*)take(64 * 4);   float* shC  = (float*)take(64 * 4);
    float* scG1 = (float*)take(512 * 4);  float* shG1 = (float*)take(512 * 4);
    float* scG2 = (float*)take(1024 * 4); float* shG2 = (float*)take(1024 * 4);
    float* part = (float*)take((size_t)8 * 8 * 1024 * 4);
    float* glob = (float*)take((size_t)8 * 1024 * 4);
    (void)ws_size; (void)in_sizes; (void)n_in; (void)out_size;

    const float invM = 1.0f / 16384.0f;

    // weight conversions (depend only on inputs) + knn up front
    wtrans_kernel<<<(64 * 512 + 255) / 256, 256, 0, stream>>>(wg1, w1T, 64, 512);
    wtrans_kernel<<<(512 * 1024 + 255) / 256, 256, 0, stream>>>(wg2, w2T, 512, 1024);
    knn_kernel<<<512, 256, 0, stream>>>(x, idx);
    cov_feat_kernel<<<64, 256, 0, stream>>>(x, idx, f19);

    // L1a: 19 -> 64
    lin19_kernel<<<4096, 256, 0, stream>>>(f19, w1a, hA);
    stats_part_kernel<<<dim3(1, STAT_NCH), 256, 0, stream>>>(hA, 64, ps, pq);
    stats_fin_kernel<<<1, 64, 0, stream>>>(ps, pq, 64, invM, g1a, b1a, scA, shA);
    bn_relu64_kernel<<<1024, 256, 0, stream>>>(hA, scA, shA);

    // L1b: 64 -> 64
    gemm_kernel<<<dim3(1, 256), 256, 0, stream>>>(hA, w1b, hB, 16384, 64, 64);
    stats_part_kernel<<<dim3(1, STAT_NCH), 256, 0, stream>>>(hB, 64, ps, pq);
    stats_fin_kernel<<<1, 64, 0, stream>>>(ps, pq, 64, invM, g1b, b1b, scB, shB);
    bn_relu64_kernel<<<1024, 256, 0, stream>>>(hB, scB, shB);

    // L1c: 64 -> 64
    gemm_kernel<<<dim3(1, 256), 256, 0, stream>>>(hB, w1c, hA, 16384, 64, 64);
    stats_part_kernel<<<dim3(1, STAT_NCH), 256, 0, stream>>>(hA, 64, ps, pq);
    stats_fin_kernel<<<1, 64, 0, stream>>>(ps, pq, 64, invM, g1c, b1c, scC, shC);
    bn_relu64_kernel<<<1024, 256, 0, stream>>>(hA, scC, shC);

    // graph pool 1: gather-max-relu(f16) then f16 MFMA 64->512 GEMM (f16 out)
    gmax1_kernel<<<4096, 256, 0, stream>>>(hA, idx, aggh64);
    hgemm_kernel<<<dim3(4, 128), 256, 0, stream>>>(aggh64, w1T, f512h, 16384, 512, 64);
    stats_part_h_kernel<<<dim3(8, STAT_NCH), 256, 0, stream>>>(f512h, 512, ps, pq);
    stats_fin_kernel<<<8, 64, 0, stream>>>(ps, pq, 512, invM, gg1, bg1, scG1, shG1);

    // graph pool 2: gather(bn)-max-relu(f16) then f16 MFMA 512->1024 GEMM (f16 out)
    gmax2_kernel<<<16384, 256, 0, stream>>>(f512h, scG1, shG1, idx, agg512h);
    hgemm_kernel<<<dim3(8, 128), 256, 0, stream>>>(agg512h, w2T, f1024h, 16384, 1024, 512);
    stats_part_h_kernel<<<dim3(16, STAT_NCH), 256, 0, stream>>>(f1024h, 1024, ps, pq);
    stats_fin_kernel<<<16, 64, 0, stream>>>(ps, pq, 1024, invM, gg2, bg2, scG2, shG2);

    // global max over N with bn applied on the fly
    globpart_kernel<<<dim3(4, 8, 8), 256, 0, stream>>>(f1024h, scG2, shG2, part);
    globred_kernel<<<dim3(4, 8), 256, 0, stream>>>(part, glob);

    // final linear + BN over 8 rows
    final_kernel<<<8, 256, 0, stream>>>(glob, w2, g2, b2, (float*)d_out);
}

// Round 9
// 399.091 us; speedup vs baseline: 1.4348x; 1.0526x over previous
//
#include <hip/hip_runtime.h>
#include <math.h>

#define EPSBN 1e-5f
#define STAT_NCH 128

typedef _Float16 half8 __attribute__((ext_vector_type(8)));
typedef _Float16 half4v __attribute__((ext_vector_type(4)));
typedef float floatx4 __attribute__((ext_vector_type(4)));

// ------------------------------------------------ KNN (top-16), 8-way chunked
// (exact round-4 version: 94 KB LDS, no VGPR cap — measured 111 us)
__global__ __launch_bounds__(512) void knn_kernel(const float* __restrict__ x,
                                                  int* __restrict__ idx)
{
    __shared__ float xs[2048], ys[2048], sq[2048];
    __shared__ float md[8][64][17];
    __shared__ int   mi[8][64][17];
    int b  = blockIdx.x >> 5;              // 32 blocks per batch
    int q0 = (blockIdx.x & 31) << 6;       // 64 queries per block
    const float* xb = x + (size_t)b * 2048 * 10;
    for (int j = threadIdx.x; j < 2048; j += 512) {
        float xj = xb[j * 10 + 0], yj = xb[j * 10 + 1];
        xs[j] = xj; ys[j] = yj;
        sq[j] = __fadd_rn(__fmul_rn(xj, xj), __fmul_rn(yj, yj));
    }
    __syncthreads();
    int lane = threadIdx.x & 63;
    int chunk = threadIdx.x >> 6;          // 0..7
    int i = q0 + lane;                     // query index within batch
    float xi = xs[i], yi = ys[i], sqi = sq[i];
    float bd[16]; int bi[16];
#pragma unroll
    for (int s = 0; s < 16; ++s) { bd[s] = INFINITY; bi[s] = 0; }
    int j0 = chunk << 8;
    for (int jj = 0; jj < 256; ++jj) {
        int j = j0 + jj;
        float dot = __fadd_rn(__fmul_rn(xi, xs[j]), __fmul_rn(yi, ys[j]));
        float d   = __fsub_rn(__fadd_rn(sqi, sq[j]), __fmul_rn(2.0f, dot));
        if (j == i) d = INFINITY;
        if (d < bd[15]) {                  // strict < : ties keep lower index
            bd[15] = d; bi[15] = j;
#pragma unroll
            for (int s = 15; s > 0; --s) {
                if (bd[s] < bd[s - 1]) {
                    float td = bd[s]; bd[s] = bd[s - 1]; bd[s - 1] = td;
                    int   ti = bi[s]; bi[s] = bi[s - 1]; bi[s - 1] = ti;
                }
            }
        }
    }
#pragma unroll
    for (int s = 0; s < 16; ++s) { md[chunk][lane][s] = bd[s]; mi[chunk][lane][s] = bi[s]; }
    __syncthreads();
    if (threadIdx.x < 64) {
        int q = threadIdx.x;
        float fd[16]; int fi[16];
#pragma unroll
        for (int s = 0; s < 16; ++s) { fd[s] = INFINITY; fi[s] = 0; }
        for (int c = 0; c < 8; ++c) {
            for (int s = 0; s < 16; ++s) {
                float d = md[c][q][s];
                if (!(d < fd[15])) break;  // sorted list: rest can't qualify
                int j = mi[c][q][s];
                fd[15] = d; fi[15] = j;
#pragma unroll
                for (int t = 15; t > 0; --t) {
                    if (fd[t] < fd[t - 1]) {
                        float td = fd[t]; fd[t] = fd[t - 1]; fd[t - 1] = td;
                        int   ti = fi[t]; fi[t] = fi[t - 1]; fi[t - 1] = ti;
                    }
                }
            }
        }
        int* out = idx + (size_t)(b * 2048 + q0 + q) * 16;
#pragma unroll
        for (int s = 0; s < 16; ++s) out[s] = fi[s];
    }
}

// ------------------------------------------------- covariance + 19-ch feature
__global__ __launch_bounds__(256) void cov_feat_kernel(const float* __restrict__ x,
                                                       const int* __restrict__ idx,
                                                       float* __restrict__ f19)
{
    int p = blockIdx.x * 256 + threadIdx.x;   // 0..16383
    int b = p >> 11;
    const float* xr = x + (size_t)p * 10;
    float v0 = xr[0], v1 = xr[1], v2 = xr[2], v3 = xr[3], v4 = xr[4];
    float v5 = xr[5], v6 = xr[6], v7 = xr[7], v8 = xr[8], v9 = xr[9];
    float e = v2 + v3 + v4 + v5 + v6 + v7 + v8 + v9;
    float sx = v0, sy = v1, se = e;
    float sxx = v0 * v0, sxy = v0 * v1, sxe = v0 * e;
    float syy = v1 * v1, sye = v1 * e, see = e * e;
    const int* ir = idx + (size_t)p * 16;
    const float* xb = x + ((size_t)(b << 11)) * 10;
#pragma unroll
    for (int k = 0; k < 16; ++k) {
        int nj = ir[k];
        const float* nr = xb + (size_t)nj * 10;
        float nx = nr[0], ny = nr[1];
        float ne = nr[2] + nr[3] + nr[4] + nr[5] + nr[6] + nr[7] + nr[8] + nr[9];
        sx += nx; sy += ny; se += ne;
        sxx += nx * nx; sxy += nx * ny; sxe += nx * ne;
        syy += ny * ny; sye += ny * ne; see += ne * ne;
    }
    const float inv = 1.0f / 17.0f;
    float mx = sx * inv, my = sy * inv, me = se * inv;
    float cxx = sxx * inv - mx * mx, cxy = sxy * inv - mx * my, cxe = sxe * inv - mx * me;
    float cyy = syy * inv - my * my, cye = sye * inv - my * me, cee = see * inv - me * me;
    float* o = f19 + (size_t)p * 19;
    o[0] = v0; o[1] = v1; o[2] = v2; o[3] = v3; o[4] = v4;
    o[5] = v5; o[6] = v6; o[7] = v7; o[8] = v8; o[9] = v9;
    o[10] = cxx; o[11] = cxy; o[12] = cxe;
    o[13] = cxy; o[14] = cyy; o[15] = cye;
    o[16] = cxe; o[17] = cye; o[18] = cee;
}

// ------------------------------------------------------------- 19->64 GEMM
__global__ __launch_bounds__(256) void lin19_kernel(const float* __restrict__ f19,
                                                    const float* __restrict__ w,
                                                    float* __restrict__ out)
{
    __shared__ float ws_[19 * 64];
    __shared__ float fr[4 * 19];
    int t = threadIdx.x;
    for (int i = t; i < 19 * 64; i += 256) ws_[i] = w[i];
    int p0 = blockIdx.x * 4;
    for (int i = t; i < 4 * 19; i += 256) fr[i] = f19[(size_t)p0 * 19 + i];
    __syncthreads();
    int lp = t >> 6, c = t & 63;
    float acc = 0.f;
#pragma unroll
    for (int k = 0; k < 19; ++k) acc = fmaf(fr[lp * 19 + k], ws_[k * 64 + c], acc);
    out[(size_t)(p0 + lp) * 64 + c] = acc;
}

// ---------------- fp32 tiled GEMM with fused input BN+ReLU on the A-load
// C[M,N] = relu(A*asc+ash) @ B[K,N]; K==64 here (scale/shift per k-column).
__global__ __launch_bounds__(256) void gemm_bn_kernel(const float* __restrict__ A,
                                                      const float* __restrict__ B,
                                                      float* __restrict__ C,
                                                      const float* __restrict__ asc,
                                                      const float* __restrict__ ash,
                                                      int M, int N, int K)
{
    __shared__ float As[16][64];   // [k][row]
    __shared__ float Bs[16][64];   // [k][col]
    __shared__ float ssc[64], ssh[64];
    int t  = threadIdx.x;
    if (t < 64) { ssc[t] = asc[t]; ssh[t] = ash[t]; }
    int m0 = blockIdx.y << 6, n0 = blockIdx.x << 6;
    int arow = t >> 2, acol = (t & 3) << 2;
    int brow = t >> 4, bcol = (t & 15) << 2;
    int tr = (t >> 4) << 2, tc = (t & 15) << 2;
    float acc[4][4] = {};
    for (int k0 = 0; k0 < K; k0 += 16) {
        float4 av = *(const float4*)(A + (size_t)(m0 + arow) * K + k0 + acol);
        float4 bv = *(const float4*)(B + (size_t)(k0 + brow) * N + n0 + bcol);
        __syncthreads();
        int ka = k0 + acol;
        As[acol + 0][arow] = fmaxf(fmaf(av.x, ssc[ka + 0], ssh[ka + 0]), 0.f);
        As[acol + 1][arow] = fmaxf(fmaf(av.y, ssc[ka + 1], ssh[ka + 1]), 0.f);
        As[acol + 2][arow] = fmaxf(fmaf(av.z, ssc[ka + 2], ssh[ka + 2]), 0.f);
        As[acol + 3][arow] = fmaxf(fmaf(av.w, ssc[ka + 3], ssh[ka + 3]), 0.f);
        *(float4*)&Bs[brow][bcol] = bv;
        __syncthreads();
#pragma unroll
        for (int kk = 0; kk < 16; ++kk) {
            float4 a = *(const float4*)&As[kk][tr];
            float4 bb = *(const float4*)&Bs[kk][tc];
            float ar[4] = {a.x, a.y, a.z, a.w};
            float br[4] = {bb.x, bb.y, bb.z, bb.w};
#pragma unroll
            for (int i = 0; i < 4; ++i)
#pragma unroll
                for (int j = 0; j < 4; ++j)
                    acc[i][j] = fmaf(ar[i], br[j], acc[i][j]);
        }
    }
#pragma unroll
    for (int i = 0; i < 4; ++i) {
        float4 o;
        o.x = acc[i][0]; o.y = acc[i][1]; o.z = acc[i][2]; o.w = acc[i][3];
        *(float4*)(C + (size_t)(m0 + tr + i) * N + n0 + tc) = o;
    }
}

// ---------------------------------------------- fp16 MFMA GEMM, 128x128 tile
// A [M][K] f16 row-major, BT [N][K] f16 row-major, C [M][N] f16. K%32==0.
__global__ __launch_bounds__(256) void hgemm_kernel(const _Float16* __restrict__ A,
                                                    const _Float16* __restrict__ BT,
                                                    _Float16* __restrict__ C,
                                                    int M, int N, int K)
{
    __shared__ __align__(16) _Float16 As[2][4][128][8];
    __shared__ __align__(16) _Float16 Bs[2][4][128][8];
    int t = threadIdx.x;
    int m0 = blockIdx.y << 7, n0 = blockIdx.x << 7;
    int wv = t >> 6, lane = t & 63;
    int fr = lane & 15, fk = lane >> 4;
    int srow = t & 63, sk8 = t >> 6;
    const _Float16* Ab = A + (size_t)m0 * K + sk8 * 8;
    const _Float16* Bb = BT + (size_t)n0 * K + sk8 * 8;

    floatx4 zero = {0.f, 0.f, 0.f, 0.f};
    floatx4 acc[2][8];
#pragma unroll
    for (int i = 0; i < 2; ++i)
#pragma unroll
        for (int j = 0; j < 8; ++j) acc[i][j] = zero;

    int NC = K >> 5;
    {
        uint4 a0 = *(const uint4*)(Ab + (size_t)srow * K);
        uint4 a1 = *(const uint4*)(Ab + (size_t)(srow + 64) * K);
        uint4 b0 = *(const uint4*)(Bb + (size_t)srow * K);
        uint4 b1 = *(const uint4*)(Bb + (size_t)(srow + 64) * K);
        *(uint4*)&As[0][sk8][srow][0]      = a0;
        *(uint4*)&As[0][sk8][srow + 64][0] = a1;
        *(uint4*)&Bs[0][sk8][srow][0]      = b0;
        *(uint4*)&Bs[0][sk8][srow + 64][0] = b1;
    }
    uint4 ra0, ra1, rb0, rb1;
    if (NC > 1) {
        ra0 = *(const uint4*)(Ab + (size_t)srow * K + 32);
        ra1 = *(const uint4*)(Ab + (size_t)(srow + 64) * K + 32);
        rb0 = *(const uint4*)(Bb + (size_t)srow * K + 32);
        rb1 = *(const uint4*)(Bb + (size_t)(srow + 64) * K + 32);
    }
    __syncthreads();

    for (int kc = 0; kc < NC; ++kc) {
        int cur = kc & 1;
        if (kc + 1 < NC) {
            int nx = cur ^ 1;
            *(uint4*)&As[nx][sk8][srow][0]      = ra0;
            *(uint4*)&As[nx][sk8][srow + 64][0] = ra1;
            *(uint4*)&Bs[nx][sk8][srow][0]      = rb0;
            *(uint4*)&Bs[nx][sk8][srow + 64][0] = rb1;
        }
        if (kc + 2 < NC) {
            int kb = (kc + 2) << 5;
            ra0 = *(const uint4*)(Ab + (size_t)srow * K + kb);
            ra1 = *(const uint4*)(Ab + (size_t)(srow + 64) * K + kb);
            rb0 = *(const uint4*)(Bb + (size_t)srow * K + kb);
            rb1 = *(const uint4*)(Bb + (size_t)(srow + 64) * K + kb);
        }
        half8 af[2];
#pragma unroll
        for (int mg = 0; mg < 2; ++mg)
            af[mg] = *(const half8*)&As[cur][fk][(wv << 5) + (mg << 4) + fr][0];
#pragma unroll
        for (int ng = 0; ng < 8; ++ng) {
            half8 bf = *(const half8*)&Bs[cur][fk][(ng << 4) + fr][0];
            acc[0][ng] = __builtin_amdgcn_mfma_f32_16x16x32_f16(af[0], bf, acc[0][ng], 0, 0, 0);
            acc[1][ng] = __builtin_amdgcn_mfma_f32_16x16x32_f16(af[1], bf, acc[1][ng], 0, 0, 0);
        }
        __syncthreads();
    }
    int orow = m0 + (wv << 5) + (fk << 2);
#pragma unroll
    for (int mg = 0; mg < 2; ++mg)
#pragma unroll
        for (int ng = 0; ng < 8; ++ng)
#pragma unroll
            for (int i = 0; i < 4; ++i)
                C[(size_t)(orow + (mg << 4) + i) * N + n0 + (ng << 4) + fr] =
                    (_Float16)acc[mg][ng][i];
}

// -------------------------------------- weight transpose+convert: wT[n][k]=w[k][n]
__global__ __launch_bounds__(256) void wtrans_kernel(const float* __restrict__ w,
                                                     _Float16* __restrict__ wT,
                                                     int K, int N)
{
    int id = blockIdx.x * 256 + threadIdx.x;
    if (id >= K * N) return;
    int k = id / N, n = id - k * N;
    wT[(size_t)n * K + k] = (_Float16)w[id];
}

// --------------------------------------------------- BN stats (f32 input)
__global__ __launch_bounds__(256) void stats_part_kernel(const float* __restrict__ X,
                                                         int C,
                                                         float* __restrict__ ps,
                                                         float* __restrict__ pq)
{
    __shared__ float sl[256][4];
    __shared__ float ql[256][4];
    int t = threadIdx.x;
    int c = (blockIdx.x << 6) + ((t & 15) << 2);
    int rowsPer = 16384 / STAT_NCH;
    int r0 = blockIdx.y * rowsPer + (t >> 4);
    int rEnd = blockIdx.y * rowsPer + rowsPer;
    float4 s = {0.f, 0.f, 0.f, 0.f}, q = {0.f, 0.f, 0.f, 0.f};
    for (int r = r0; r < rEnd; r += 16) {
        float4 v = *(const float4*)(X + (size_t)r * C + c);
        s.x += v.x; s.y += v.y; s.z += v.z; s.w += v.w;
        q.x = fmaf(v.x, v.x, q.x); q.y = fmaf(v.y, v.y, q.y);
        q.z = fmaf(v.z, v.z, q.z); q.w = fmaf(v.w, v.w, q.w);
    }
    sl[t][0] = s.x; sl[t][1] = s.y; sl[t][2] = s.z; sl[t][3] = s.w;
    ql[t][0] = q.x; ql[t][1] = q.y; ql[t][2] = q.z; ql[t][3] = q.w;
    __syncthreads();
    if (t < 64) {
        int comp = t & 3, grp = t >> 2;
        float ss = 0.f, qq = 0.f;
#pragma unroll
        for (int g = 0; g < 16; ++g) {
            ss += sl[grp + (g << 4)][comp];
            qq += ql[grp + (g << 4)][comp];
        }
        ps[(size_t)blockIdx.y * C + (blockIdx.x << 6) + t] = ss;
        pq[(size_t)blockIdx.y * C + (blockIdx.x << 6) + t] = qq;
    }
}

// --------------------------------------------------- BN stats (f16 input)
__global__ __launch_bounds__(256) void stats_part_h_kernel(const _Float16* __restrict__ X,
                                                           int C,
                                                           float* __restrict__ ps,
                                                           float* __restrict__ pq)
{
    __shared__ float sl[256][4];
    __shared__ float ql[256][4];
    int t = threadIdx.x;
    int c = (blockIdx.x << 6) + ((t & 15) << 2);
    int rowsPer = 16384 / STAT_NCH;
    int r0 = blockIdx.y * rowsPer + (t >> 4);
    int rEnd = blockIdx.y * rowsPer + rowsPer;
    float4 s = {0.f, 0.f, 0.f, 0.f}, q = {0.f, 0.f, 0.f, 0.f};
    for (int r = r0; r < rEnd; r += 16) {
        half4v hv = *(const half4v*)(X + (size_t)r * C + c);
        float v0 = (float)hv[0], v1 = (float)hv[1], v2 = (float)hv[2], v3 = (float)hv[3];
        s.x += v0; s.y += v1; s.z += v2; s.w += v3;
        q.x = fmaf(v0, v0, q.x); q.y = fmaf(v1, v1, q.y);
        q.z = fmaf(v2, v2, q.z); q.w = fmaf(v3, v3, q.w);
    }
    sl[t][0] = s.x; sl[t][1] = s.y; sl[t][2] = s.z; sl[t][3] = s.w;
    ql[t][0] = q.x; ql[t][1] = q.y; ql[t][2] = q.z; ql[t][3] = q.w;
    __syncthreads();
    if (t < 64) {
        int comp = t & 3, grp = t >> 2;
        float ss = 0.f, qq = 0.f;
#pragma unroll
        for (int g = 0; g < 16; ++g) {
            ss += sl[grp + (g << 4)][comp];
            qq += ql[grp + (g << 4)][comp];
        }
        ps[(size_t)blockIdx.y * C + (blockIdx.x << 6) + t] = ss;
        pq[(size_t)blockIdx.y * C + (blockIdx.x << 6) + t] = qq;
    }
}

__global__ __launch_bounds__(64) void stats_fin_kernel(const float* __restrict__ ps,
                                                       const float* __restrict__ pq,
                                                       int C, float invM,
                                                       const float* __restrict__ g,
                                                       const float* __restrict__ bb,
                                                       float* __restrict__ scale,
                                                       float* __restrict__ shift)
{
    int c = blockIdx.x * 64 + threadIdx.x;
    float s = 0.f, q = 0.f;
    for (int ch = 0; ch < STAT_NCH; ++ch) { s += ps[(size_t)ch * C + c]; q += pq[(size_t)ch * C + c]; }
    float m  = s * invM;
    float v  = fmaxf(q * invM - m * m, 0.f);
    float sc = g[c] / sqrtf(v + EPSBN);
    scale[c] = sc;
    shift[c] = bb[c] - m * sc;
}

// ---------- gather + bn on the fly + max + relu, C=64 f32 raw -> f16 output
__global__ __launch_bounds__(256) void gmax1_kernel(const float* __restrict__ f,
                                                    const float* __restrict__ scale,
                                                    const float* __restrict__ shift,
                                                    const int* __restrict__ idx,
                                                    _Float16* __restrict__ agg)
{
    int t = threadIdx.x;
    int p = blockIdx.x * 4 + (t >> 6);
    int c = t & 63;
    int b = p >> 11;
    float sc = scale[c], sh = shift[c];
    const int* ir = idx + (size_t)p * 16;
    const float* fb = f + ((size_t)(b << 11)) * 64;
    float m = -INFINITY;
#pragma unroll
    for (int k = 0; k < 16; ++k) {
        int nj = ir[k];
        m = fmaxf(m, fmaf(fb[(size_t)nj * 64 + c], sc, sh));
    }
    agg[(size_t)p * 64 + c] = (_Float16)fmaxf(m, 0.f);
}

// ------------- gather(f16) + bn on the fly + max + relu, C=512 -> f16 output
__global__ __launch_bounds__(256) void gmax2_kernel(const _Float16* __restrict__ f,
                                                    const float* __restrict__ scale,
                                                    const float* __restrict__ shift,
                                                    const int* __restrict__ idx,
                                                    _Float16* __restrict__ agg)
{
    int t = threadIdx.x;
    int p = blockIdx.x;
    int b = p >> 11;
    int c0 = t, c1 = t + 256;
    float s0 = scale[c0], h0 = shift[c0], s1 = scale[c1], h1 = shift[c1];
    const int* ir = idx + (size_t)p * 16;
    const _Float16* fb = f + ((size_t)(b << 11)) * 512;
    float m0 = -INFINITY, m1 = -INFINITY;
#pragma unroll
    for (int k = 0; k < 16; ++k) {
        int nj = ir[k];
        const _Float16* row = fb + (size_t)nj * 512;
        m0 = fmaxf(m0, fmaf((float)row[c0], s0, h0));
        m1 = fmaxf(m1, fmaf((float)row[c1], s1, h1));
    }
    _Float16* o = agg + (size_t)p * 512;
    o[c0] = (_Float16)fmaxf(m0, 0.f);
    o[c1] = (_Float16)fmaxf(m1, 0.f);
}

// ---------------- global max over N with bn applied (C=1024, f16 input)
__global__ __launch_bounds__(256) void globpart_kernel(const _Float16* __restrict__ f,
                                                       const float* __restrict__ scale,
                                                       const float* __restrict__ shift,
                                                       float* __restrict__ part)
{
    int c = blockIdx.x * 256 + threadIdx.x;
    int b = blockIdx.z, ch = blockIdx.y;
    float sc = scale[c], sh = shift[c];
    const _Float16* fb = f + ((size_t)(b << 11) + ch * 256) * 1024;
    float m = -INFINITY;
    for (int n = 0; n < 256; ++n)
        m = fmaxf(m, fmaf((float)fb[(size_t)n * 1024 + c], sc, sh));
    part[((size_t)(b * 8 + ch)) * 1024 + c] = m;
}

__global__ __launch_bounds__(256) void globred_kernel(const float* __restrict__ part,
                                                      float* __restrict__ glob)
{
    int c = blockIdx.x * 256 + threadIdx.x;
    int b = blockIdx.y;
    float m = -INFINITY;
#pragma unroll
    for (int ch = 0; ch < 8; ++ch)
        m = fmaxf(m, part[((size_t)(b * 8 + ch)) * 1024 + c]);
    glob[(size_t)b * 1024 + c] = m;
}

// ---------------------------------------- final (8x1024)@(1024x512) + BN(8)
__global__ __launch_bounds__(256) void final_kernel(const float* __restrict__ glob,
                                                    const float* __restrict__ w2,
                                                    const float* __restrict__ g,
                                                    const float* __restrict__ bb,
                                                    float* __restrict__ out)
{
    __shared__ float vals[8][64];
    int t  = threadIdx.x;
    int c0 = blockIdx.x * 64;
    int r  = t >> 5, cl = t & 31;
    const float* gr = glob + (size_t)r * 1024;
    float a0 = 0.f, a1 = 0.f;
    int ca = c0 + cl, cb = c0 + cl + 32;
    for (int k = 0; k < 1024; ++k) {
        float gv = gr[k];
        a0 = fmaf(gv, w2[(size_t)k * 512 + ca], a0);
        a1 = fmaf(gv, w2[(size_t)k * 512 + cb], a1);
    }
    vals[r][cl] = a0; vals[r][cl + 32] = a1;
    __syncthreads();
    if (t < 64) {
        int c = c0 + t;
        float s = 0.f;
#pragma unroll
        for (int rr = 0; rr < 8; ++rr) s += vals[rr][t];
        float m = s * 0.125f;
        float v = 0.f;
#pragma unroll
        for (int rr = 0; rr < 8; ++rr) { float d = vals[rr][t] - m; v = fmaf(d, d, v); }
        v *= 0.125f;
        float sc = g[c] / sqrtf(v + EPSBN);
#pragma unroll
        for (int rr = 0; rr < 8; ++rr)
            out[(size_t)rr * 512 + c] = fmaf(vals[rr][t] - m, sc, bb[c]);
    }
}

// =============================================================== launch
extern "C" void kernel_launch(void* const* d_in, const int* in_sizes, int n_in,
                              void* d_out, int out_size, void* d_ws, size_t ws_size,
                              hipStream_t stream)
{
    const float* x   = (const float*)d_in[0];
    const float* w1a = (const float*)d_in[1];
    const float* g1a = (const float*)d_in[2];
    const float* b1a = (const float*)d_in[3];
    const float* w1b = (const float*)d_in[4];
    const float* g1b = (const float*)d_in[5];
    const float* b1b = (const float*)d_in[6];
    const float* w1c = (const float*)d_in[7];
    const float* g1c = (const float*)d_in[8];
    const float* b1c = (const float*)d_in[9];
    const float* wg1 = (const float*)d_in[10];
    const float* gg1 = (const float*)d_in[11];
    const float* bg1 = (const float*)d_in[12];
    const float* wg2 = (const float*)d_in[13];
    const float* gg2 = (const float*)d_in[14];
    const float* bg2 = (const float*)d_in[15];
    const float* w2  = (const float*)d_in[16];
    const float* g2  = (const float*)d_in[17];
    const float* b2  = (const float*)d_in[18];

    char* w = (char*)d_ws;
    size_t off = 0;
    auto take = [&](size_t bytes) -> char* {
        char* p = w + off;
        off += (bytes + 255) & ~(size_t)255;
        return p;
    };
    int*       idx     = (int*)      take((size_t)16384 * 16 * 4);
    float*     f19     = (float*)    take((size_t)16384 * 19 * 4);
    float*     h0      = (float*)    take((size_t)16384 * 64 * 4);
    float*     h1      = (float*)    take((size_t)16384 * 64 * 4);
    float*     h2      = (float*)    take((size_t)16384 * 64 * 4);
    _Float16*  f512h   = (_Float16*) take((size_t)16384 * 512 * 2);
    _Float16*  f1024h  = (_Float16*) take((size_t)16384 * 1024 * 2);
    _Float16*  aggh64  = (_Float16*) take((size_t)16384 * 64 * 2);
    _Float16*  agg512h = (_Float16*) take((size_t)16384 * 512 * 2);
    _Float16*  w1T     = (_Float16*) take((size_t)512 * 64 * 2);
    _Float16*  w2T     = (_Float16*) take((size_t)1024 * 512 * 2);
    float*     ps      = (float*)    take((size_t)STAT_NCH * 1024 * 4);
    float*     pq      = (float*)    take((size_t)STAT_NCH * 1024 * 4);
    float* scA  = (float*)take(64 * 4);   float* shA  = (float*)take(64 * 4);
    float* scB  = (float*)take(64 * 4);   float* shB  = (float*)take(64 * 4);
    float* scC  = (float*)take(64 * 4);   float* shC  = (float*)take(64 * 4);
    float* scG1 = (float*)take(512 * 4);  float* shG1 = (float*)take(512 * 4);
    float* scG2 = (float*)take(1024 * 4); float* shG2 = (float*)take(1024 * 4);
    float* part = (float*)take((size_t)8 * 8 * 1024 * 4);
    float* glob = (float*)take((size_t)8 * 1024 * 4);
    (void)ws_size; (void)in_sizes; (void)n_in; (void)out_size;

    const float invM = 1.0f / 16384.0f;

    // weight conversions (depend only on inputs) + knn up front
    wtrans_kernel<<<(64 * 512 + 255) / 256, 256, 0, stream>>>(wg1, w1T, 64, 512);
    wtrans_kernel<<<(512 * 1024 + 255) / 256, 256, 0, stream>>>(wg2, w2T, 512, 1024);
    knn_kernel<<<256, 512, 0, stream>>>(x, idx);
    cov_feat_kernel<<<64, 256, 0, stream>>>(x, idx, f19);

    // L1a: 19 -> 64 (raw out) + stats
    lin19_kernel<<<4096, 256, 0, stream>>>(f19, w1a, h0);
    stats_part_kernel<<<dim3(1, STAT_NCH), 256, 0, stream>>>(h0, 64, ps, pq);
    stats_fin_kernel<<<1, 64, 0, stream>>>(ps, pq, 64, invM, g1a, b1a, scA, shA);

    // L1b: bn_relu(h0) @ w1b -> h1 raw, stats on h1
    gemm_bn_kernel<<<dim3(1, 256), 256, 0, stream>>>(h0, w1b, h1, scA, shA, 16384, 64, 64);
    stats_part_kernel<<<dim3(1, STAT_NCH), 256, 0, stream>>>(h1, 64, ps, pq);
    stats_fin_kernel<<<1, 64, 0, stream>>>(ps, pq, 64, invM, g1b, b1b, scB, shB);

    // L1c: bn_relu(h1) @ w1c -> h2 raw, stats on h2
    gemm_bn_kernel<<<dim3(1, 256), 256, 0, stream>>>(h1, w1c, h2, scB, shB, 16384, 64, 64);
    stats_part_kernel<<<dim3(1, STAT_NCH), 256, 0, stream>>>(h2, 64, ps, pq);
    stats_fin_kernel<<<1, 64, 0, stream>>>(ps, pq, 64, invM, g1c, b1c, scC, shC);

    // graph pool 1: gather(bn(h2))-max-relu(f16) then f16 MFMA 64->512 (f16 out)
    gmax1_kernel<<<4096, 256, 0, stream>>>(h2, scC, shC, idx, aggh64);
    hgemm_kernel<<<dim3(4, 128), 256, 0, stream>>>(aggh64, w1T, f512h, 16384, 512, 64);
    stats_part_h_kernel<<<dim3(8, STAT_NCH), 256, 0, stream>>>(f512h, 512, ps, pq);
    stats_fin_kernel<<<8, 64, 0, stream>>>(ps, pq, 512, invM, gg1, bg1, scG1, shG1);

    // graph pool 2: gather(bn)-max-relu(f16) then f16 MFMA 512->1024 (f16 out)
    gmax2_kernel<<<16384, 256, 0, stream>>>(f512h, scG1, shG1, idx, agg512h);
    hgemm_kernel<<<dim3(8, 128), 256, 0, stream>>>(agg512h, w2T, f1024h, 16384, 1024, 512);
    stats_part_h_kernel<<<dim3(16, STAT_NCH), 256, 0, stream>>>(f1024h, 1024, ps, pq);
    stats_fin_kernel<<<16, 64, 0, stream>>>(ps, pq, 1024, invM, gg2, bg2, scG2, shG2);

    // global max over N with bn applied on the fly
    globpart_kernel<<<dim3(4, 8, 8), 256, 0, stream>>>(f1024h, scG2, shG2, part);
    globred_kernel<<<dim3(4, 8), 256, 0, stream>>>(part, glob);

    // final linear + BN over 8 rows
    final_kernel<<<8, 256, 0, stream>>>(glob, w2, g2, b2, (float*)d_out);
}

// Round 10
// 363.623 us; speedup vs baseline: 1.5748x; 1.0975x over previous
//
#include <hip/hip_runtime.h>
#include <math.h>

#define EPSBN 1e-5f
#define STAT_NCH 128

typedef _Float16 half8 __attribute__((ext_vector_type(8)));
typedef _Float16 half4v __attribute__((ext_vector_type(4)));
typedef float floatx4 __attribute__((ext_vector_type(4)));

// ------------------------------------------------ KNN (top-16), 8-way chunked
// (exact round-4 version: 94 KB LDS, no VGPR cap — measured 111 us)
__global__ __launch_bounds__(512) void knn_kernel(const float* __restrict__ x,
                                                  int* __restrict__ idx)
{
    __shared__ float xs[2048], ys[2048], sq[2048];
    __shared__ float md[8][64][17];
    __shared__ int   mi[8][64][17];
    int b  = blockIdx.x >> 5;              // 32 blocks per batch
    int q0 = (blockIdx.x & 31) << 6;       // 64 queries per block
    const float* xb = x + (size_t)b * 2048 * 10;
    for (int j = threadIdx.x; j < 2048; j += 512) {
        float xj = xb[j * 10 + 0], yj = xb[j * 10 + 1];
        xs[j] = xj; ys[j] = yj;
        sq[j] = __fadd_rn(__fmul_rn(xj, xj), __fmul_rn(yj, yj));
    }
    __syncthreads();
    int lane = threadIdx.x & 63;
    int chunk = threadIdx.x >> 6;          // 0..7
    int i = q0 + lane;                     // query index within batch
    float xi = xs[i], yi = ys[i], sqi = sq[i];
    float bd[16]; int bi[16];
#pragma unroll
    for (int s = 0; s < 16; ++s) { bd[s] = INFINITY; bi[s] = 0; }
    int j0 = chunk << 8;
    for (int jj = 0; jj < 256; ++jj) {
        int j = j0 + jj;
        float dot = __fadd_rn(__fmul_rn(xi, xs[j]), __fmul_rn(yi, ys[j]));
        float d   = __fsub_rn(__fadd_rn(sqi, sq[j]), __fmul_rn(2.0f, dot));
        if (j == i) d = INFINITY;
        if (d < bd[15]) {                  // strict < : ties keep lower index
            bd[15] = d; bi[15] = j;
#pragma unroll
            for (int s = 15; s > 0; --s) {
                if (bd[s] < bd[s - 1]) {
                    float td = bd[s]; bd[s] = bd[s - 1]; bd[s - 1] = td;
                    int   ti = bi[s]; bi[s] = bi[s - 1]; bi[s - 1] = ti;
                }
            }
        }
    }
#pragma unroll
    for (int s = 0; s < 16; ++s) { md[chunk][lane][s] = bd[s]; mi[chunk][lane][s] = bi[s]; }
    __syncthreads();
    if (threadIdx.x < 64) {
        int q = threadIdx.x;
        float fd[16]; int fi[16];
#pragma unroll
        for (int s = 0; s < 16; ++s) { fd[s] = INFINITY; fi[s] = 0; }
        for (int c = 0; c < 8; ++c) {
            for (int s = 0; s < 16; ++s) {
                float d = md[c][q][s];
                if (!(d < fd[15])) break;  // sorted list: rest can't qualify
                int j = mi[c][q][s];
                fd[15] = d; fi[15] = j;
#pragma unroll
                for (int t = 15; t > 0; --t) {
                    if (fd[t] < fd[t - 1]) {
                        float td = fd[t]; fd[t] = fd[t - 1]; fd[t - 1] = td;
                        int   ti = fi[t]; fi[t] = fi[t - 1]; fi[t - 1] = ti;
                    }
                }
            }
        }
        int* out = idx + (size_t)(b * 2048 + q0 + q) * 16;
#pragma unroll
        for (int s = 0; s < 16; ++s) out[s] = fi[s];
    }
}

// ------------------------------------------------- covariance + 19-ch feature
__global__ __launch_bounds__(256) void cov_feat_kernel(const float* __restrict__ x,
                                                       const int* __restrict__ idx,
                                                       float* __restrict__ f19)
{
    int p = blockIdx.x * 256 + threadIdx.x;   // 0..16383
    int b = p >> 11;
    const float* xr = x + (size_t)p * 10;
    float v0 = xr[0], v1 = xr[1], v2 = xr[2], v3 = xr[3], v4 = xr[4];
    float v5 = xr[5], v6 = xr[6], v7 = xr[7], v8 = xr[8], v9 = xr[9];
    float e = v2 + v3 + v4 + v5 + v6 + v7 + v8 + v9;
    float sx = v0, sy = v1, se = e;
    float sxx = v0 * v0, sxy = v0 * v1, sxe = v0 * e;
    float syy = v1 * v1, sye = v1 * e, see = e * e;
    const int* ir = idx + (size_t)p * 16;
    const float* xb = x + ((size_t)(b << 11)) * 10;
#pragma unroll
    for (int k = 0; k < 16; ++k) {
        int nj = ir[k];
        const float* nr = xb + (size_t)nj * 10;
        float nx = nr[0], ny = nr[1];
        float ne = nr[2] + nr[3] + nr[4] + nr[5] + nr[6] + nr[7] + nr[8] + nr[9];
        sx += nx; sy += ny; se += ne;
        sxx += nx * nx; sxy += nx * ny; sxe += nx * ne;
        syy += ny * ny; sye += ny * ne; see += ne * ne;
    }
    const float inv = 1.0f / 17.0f;
    float mx = sx * inv, my = sy * inv, me = se * inv;
    float cxx = sxx * inv - mx * mx, cxy = sxy * inv - mx * my, cxe = sxe * inv - mx * me;
    float cyy = syy * inv - my * my, cye = sye * inv - my * me, cee = see * inv - me * me;
    float* o = f19 + (size_t)p * 19;
    o[0] = v0; o[1] = v1; o[2] = v2; o[3] = v3; o[4] = v4;
    o[5] = v5; o[6] = v6; o[7] = v7; o[8] = v8; o[9] = v9;
    o[10] = cxx; o[11] = cxy; o[12] = cxe;
    o[13] = cxy; o[14] = cyy; o[15] = cye;
    o[16] = cxe; o[17] = cye; o[18] = cee;
}

// ------------------------------------------------------------- 19->64 GEMM
__global__ __launch_bounds__(256) void lin19_kernel(const float* __restrict__ f19,
                                                    const float* __restrict__ w,
                                                    float* __restrict__ out)
{
    __shared__ float ws_[19 * 64];
    __shared__ float fr[4 * 19];
    int t = threadIdx.x;
    for (int i = t; i < 19 * 64; i += 256) ws_[i] = w[i];
    int p0 = blockIdx.x * 4;
    for (int i = t; i < 4 * 19; i += 256) fr[i] = f19[(size_t)p0 * 19 + i];
    __syncthreads();
    int lp = t >> 6, c = t & 63;
    float acc = 0.f;
#pragma unroll
    for (int k = 0; k < 19; ++k) acc = fmaf(fr[lp * 19 + k], ws_[k * 64 + c], acc);
    out[(size_t)(p0 + lp) * 64 + c] = acc;
}

// ---------------- fp32 tiled GEMM with fused input BN+ReLU on the A-load
__global__ __launch_bounds__(256) void gemm_bn_kernel(const float* __restrict__ A,
                                                      const float* __restrict__ B,
                                                      float* __restrict__ C,
                                                      const float* __restrict__ asc,
                                                      const float* __restrict__ ash,
                                                      int M, int N, int K)
{
    __shared__ float As[16][64];   // [k][row]
    __shared__ float Bs[16][64];   // [k][col]
    __shared__ float ssc[64], ssh[64];
    int t  = threadIdx.x;
    if (t < 64) { ssc[t] = asc[t]; ssh[t] = ash[t]; }
    int m0 = blockIdx.y << 6, n0 = blockIdx.x << 6;
    int arow = t >> 2, acol = (t & 3) << 2;
    int brow = t >> 4, bcol = (t & 15) << 2;
    int tr = (t >> 4) << 2, tc = (t & 15) << 2;
    float acc[4][4] = {};
    for (int k0 = 0; k0 < K; k0 += 16) {
        float4 av = *(const float4*)(A + (size_t)(m0 + arow) * K + k0 + acol);
        float4 bv = *(const float4*)(B + (size_t)(k0 + brow) * N + n0 + bcol);
        __syncthreads();
        int ka = k0 + acol;
        As[acol + 0][arow] = fmaxf(fmaf(av.x, ssc[ka + 0], ssh[ka + 0]), 0.f);
        As[acol + 1][arow] = fmaxf(fmaf(av.y, ssc[ka + 1], ssh[ka + 1]), 0.f);
        As[acol + 2][arow] = fmaxf(fmaf(av.z, ssc[ka + 2], ssh[ka + 2]), 0.f);
        As[acol + 3][arow] = fmaxf(fmaf(av.w, ssc[ka + 3], ssh[ka + 3]), 0.f);
        *(float4*)&Bs[brow][bcol] = bv;
        __syncthreads();
#pragma unroll
        for (int kk = 0; kk < 16; ++kk) {
            float4 a = *(const float4*)&As[kk][tr];
            float4 bb = *(const float4*)&Bs[kk][tc];
            float ar[4] = {a.x, a.y, a.z, a.w};
            float br[4] = {bb.x, bb.y, bb.z, bb.w};
#pragma unroll
            for (int i = 0; i < 4; ++i)
#pragma unroll
                for (int j = 0; j < 4; ++j)
                    acc[i][j] = fmaf(ar[i], br[j], acc[i][j]);
        }
    }
#pragma unroll
    for (int i = 0; i < 4; ++i) {
        float4 o;
        o.x = acc[i][0]; o.y = acc[i][1]; o.z = acc[i][2]; o.w = acc[i][3];
        *(float4*)(C + (size_t)(m0 + tr + i) * N + n0 + tc) = o;
    }
}

// ---------------------------------------------- fp16 MFMA GEMM, 128x128 tile
__global__ __launch_bounds__(256) void hgemm_kernel(const _Float16* __restrict__ A,
                                                    const _Float16* __restrict__ BT,
                                                    _Float16* __restrict__ C,
                                                    int M, int N, int K)
{
    __shared__ __align__(16) _Float16 As[2][4][128][8];
    __shared__ __align__(16) _Float16 Bs[2][4][128][8];
    int t = threadIdx.x;
    int m0 = blockIdx.y << 7, n0 = blockIdx.x << 7;
    int wv = t >> 6, lane = t & 63;
    int fr = lane & 15, fk = lane >> 4;
    int srow = t & 63, sk8 = t >> 6;
    const _Float16* Ab = A + (size_t)m0 * K + sk8 * 8;
    const _Float16* Bb = BT + (size_t)n0 * K + sk8 * 8;

    floatx4 zero = {0.f, 0.f, 0.f, 0.f};
    floatx4 acc[2][8];
#pragma unroll
    for (int i = 0; i < 2; ++i)
#pragma unroll
        for (int j = 0; j < 8; ++j) acc[i][j] = zero;

    int NC = K >> 5;
    {
        uint4 a0 = *(const uint4*)(Ab + (size_t)srow * K);
        uint4 a1 = *(const uint4*)(Ab + (size_t)(srow + 64) * K);
        uint4 b0 = *(const uint4*)(Bb + (size_t)srow * K);
        uint4 b1 = *(const uint4*)(Bb + (size_t)(srow + 64) * K);
        *(uint4*)&As[0][sk8][srow][0]      = a0;
        *(uint4*)&As[0][sk8][srow + 64][0] = a1;
        *(uint4*)&Bs[0][sk8][srow][0]      = b0;
        *(uint4*)&Bs[0][sk8][srow + 64][0] = b1;
    }
    uint4 ra0, ra1, rb0, rb1;
    if (NC > 1) {
        ra0 = *(const uint4*)(Ab + (size_t)srow * K + 32);
        ra1 = *(const uint4*)(Ab + (size_t)(srow + 64) * K + 32);
        rb0 = *(const uint4*)(Bb + (size_t)srow * K + 32);
        rb1 = *(const uint4*)(Bb + (size_t)(srow + 64) * K + 32);
    }
    __syncthreads();

    for (int kc = 0; kc < NC; ++kc) {
        int cur = kc & 1;
        if (kc + 1 < NC) {
            int nx = cur ^ 1;
            *(uint4*)&As[nx][sk8][srow][0]      = ra0;
            *(uint4*)&As[nx][sk8][srow + 64][0] = ra1;
            *(uint4*)&Bs[nx][sk8][srow][0]      = rb0;
            *(uint4*)&Bs[nx][sk8][srow + 64][0] = rb1;
        }
        if (kc + 2 < NC) {
            int kb = (kc + 2) << 5;
            ra0 = *(const uint4*)(Ab + (size_t)srow * K + kb);
            ra1 = *(const uint4*)(Ab + (size_t)(srow + 64) * K + kb);
            rb0 = *(const uint4*)(Bb + (size_t)srow * K + kb);
            rb1 = *(const uint4*)(Bb + (size_t)(srow + 64) * K + kb);
        }
        half8 af[2];
#pragma unroll
        for (int mg = 0; mg < 2; ++mg)
            af[mg] = *(const half8*)&As[cur][fk][(wv << 5) + (mg << 4) + fr][0];
#pragma unroll
        for (int ng = 0; ng < 8; ++ng) {
            half8 bf = *(const half8*)&Bs[cur][fk][(ng << 4) + fr][0];
            acc[0][ng] = __builtin_amdgcn_mfma_f32_16x16x32_f16(af[0], bf, acc[0][ng], 0, 0, 0);
            acc[1][ng] = __builtin_amdgcn_mfma_f32_16x16x32_f16(af[1], bf, acc[1][ng], 0, 0, 0);
        }
        __syncthreads();
    }
    int orow = m0 + (wv << 5) + (fk << 2);
#pragma unroll
    for (int mg = 0; mg < 2; ++mg)
#pragma unroll
        for (int ng = 0; ng < 8; ++ng)
#pragma unroll
            for (int i = 0; i < 4; ++i)
                C[(size_t)(orow + (mg << 4) + i) * N + n0 + (ng << 4) + fr] =
                    (_Float16)acc[mg][ng][i];
}

// -------------------------------------- weight transpose+convert: wT[n][k]=w[k][n]
__global__ __launch_bounds__(256) void wtrans_kernel(const float* __restrict__ w,
                                                     _Float16* __restrict__ wT,
                                                     int K, int N)
{
    int id = blockIdx.x * 256 + threadIdx.x;
    if (id >= K * N) return;
    int k = id / N, n = id - k * N;
    wT[(size_t)n * K + k] = (_Float16)w[id];
}

// --------------------------------------------------- BN stats (f32 input)
__global__ __launch_bounds__(256) void stats_part_kernel(const float* __restrict__ X,
                                                         int C,
                                                         float* __restrict__ ps,
                                                         float* __restrict__ pq)
{
    __shared__ float sl[256][4];
    __shared__ float ql[256][4];
    int t = threadIdx.x;
    int c = (blockIdx.x << 6) + ((t & 15) << 2);
    int rowsPer = 16384 / STAT_NCH;
    int r0 = blockIdx.y * rowsPer + (t >> 4);
    int rEnd = blockIdx.y * rowsPer + rowsPer;
    float4 s = {0.f, 0.f, 0.f, 0.f}, q = {0.f, 0.f, 0.f, 0.f};
    for (int r = r0; r < rEnd; r += 16) {
        float4 v = *(const float4*)(X + (size_t)r * C + c);
        s.x += v.x; s.y += v.y; s.z += v.z; s.w += v.w;
        q.x = fmaf(v.x, v.x, q.x); q.y = fmaf(v.y, v.y, q.y);
        q.z = fmaf(v.z, v.z, q.z); q.w = fmaf(v.w, v.w, q.w);
    }
    sl[t][0] = s.x; sl[t][1] = s.y; sl[t][2] = s.z; sl[t][3] = s.w;
    ql[t][0] = q.x; ql[t][1] = q.y; ql[t][2] = q.z; ql[t][3] = q.w;
    __syncthreads();
    if (t < 64) {
        int comp = t & 3, grp = t >> 2;
        float ss = 0.f, qq = 0.f;
#pragma unroll
        for (int g = 0; g < 16; ++g) {
            ss += sl[grp + (g << 4)][comp];
            qq += ql[grp + (g << 4)][comp];
        }
        ps[(size_t)blockIdx.y * C + (blockIdx.x << 6) + t] = ss;
        pq[(size_t)blockIdx.y * C + (blockIdx.x << 6) + t] = qq;
    }
}

// --------------------------------------------------- BN stats (f16 input)
__global__ __launch_bounds__(256) void stats_part_h_kernel(const _Float16* __restrict__ X,
                                                           int C,
                                                           float* __restrict__ ps,
                                                           float* __restrict__ pq)
{
    __shared__ float sl[256][4];
    __shared__ float ql[256][4];
    int t = threadIdx.x;
    int c = (blockIdx.x << 6) + ((t & 15) << 2);
    int rowsPer = 16384 / STAT_NCH;
    int r0 = blockIdx.y * rowsPer + (t >> 4);
    int rEnd = blockIdx.y * rowsPer + rowsPer;
    float4 s = {0.f, 0.f, 0.f, 0.f}, q = {0.f, 0.f, 0.f, 0.f};
    for (int r = r0; r < rEnd; r += 16) {
        half4v hv = *(const half4v*)(X + (size_t)r * C + c);
        float v0 = (float)hv[0], v1 = (float)hv[1], v2 = (float)hv[2], v3 = (float)hv[3];
        s.x += v0; s.y += v1; s.z += v2; s.w += v3;
        q.x = fmaf(v0, v0, q.x); q.y = fmaf(v1, v1, q.y);
        q.z = fmaf(v2, v2, q.z); q.w = fmaf(v3, v3, q.w);
    }
    sl[t][0] = s.x; sl[t][1] = s.y; sl[t][2] = s.z; sl[t][3] = s.w;
    ql[t][0] = q.x; ql[t][1] = q.y; ql[t][2] = q.z; ql[t][3] = q.w;
    __syncthreads();
    if (t < 64) {
        int comp = t & 3, grp = t >> 2;
        float ss = 0.f, qq = 0.f;
#pragma unroll
        for (int g = 0; g < 16; ++g) {
            ss += sl[grp + (g << 4)][comp];
            qq += ql[grp + (g << 4)][comp];
        }
        ps[(size_t)blockIdx.y * C + (blockIdx.x << 6) + t] = ss;
        pq[(size_t)blockIdx.y * C + (blockIdx.x << 6) + t] = qq;
    }
}

// ------------- BN stats + per-chunk raw max/min (f16 input, for f1024 path)
__global__ __launch_bounds__(256) void stats_minmax_part_h_kernel(const _Float16* __restrict__ X,
                                                                  int C,
                                                                  float* __restrict__ ps,
                                                                  float* __restrict__ pq,
                                                                  float* __restrict__ pmx,
                                                                  float* __restrict__ pmn)
{
    __shared__ float sl[256][4];
    __shared__ float ql[256][4];
    __shared__ float xl[256][4];
    __shared__ float nl[256][4];
    int t = threadIdx.x;
    int c = (blockIdx.x << 6) + ((t & 15) << 2);
    int rowsPer = 16384 / STAT_NCH;
    int r0 = blockIdx.y * rowsPer + (t >> 4);
    int rEnd = blockIdx.y * rowsPer + rowsPer;
    float4 s = {0.f, 0.f, 0.f, 0.f}, q = {0.f, 0.f, 0.f, 0.f};
    float4 mx = {-INFINITY, -INFINITY, -INFINITY, -INFINITY};
    float4 mn = {INFINITY, INFINITY, INFINITY, INFINITY};
    for (int r = r0; r < rEnd; r += 16) {
        half4v hv = *(const half4v*)(X + (size_t)r * C + c);
        float v0 = (float)hv[0], v1 = (float)hv[1], v2 = (float)hv[2], v3 = (float)hv[3];
        s.x += v0; s.y += v1; s.z += v2; s.w += v3;
        q.x = fmaf(v0, v0, q.x); q.y = fmaf(v1, v1, q.y);
        q.z = fmaf(v2, v2, q.z); q.w = fmaf(v3, v3, q.w);
        mx.x = fmaxf(mx.x, v0); mx.y = fmaxf(mx.y, v1);
        mx.z = fmaxf(mx.z, v2); mx.w = fmaxf(mx.w, v3);
        mn.x = fminf(mn.x, v0); mn.y = fminf(mn.y, v1);
        mn.z = fminf(mn.z, v2); mn.w = fminf(mn.w, v3);
    }
    sl[t][0] = s.x; sl[t][1] = s.y; sl[t][2] = s.z; sl[t][3] = s.w;
    ql[t][0] = q.x; ql[t][1] = q.y; ql[t][2] = q.z; ql[t][3] = q.w;
    xl[t][0] = mx.x; xl[t][1] = mx.y; xl[t][2] = mx.z; xl[t][3] = mx.w;
    nl[t][0] = mn.x; nl[t][1] = mn.y; nl[t][2] = mn.z; nl[t][3] = mn.w;
    __syncthreads();
    if (t < 64) {
        int comp = t & 3, grp = t >> 2;
        float ss = 0.f, qq = 0.f, xx = -INFINITY, nn = INFINITY;
#pragma unroll
        for (int g = 0; g < 16; ++g) {
            ss += sl[grp + (g << 4)][comp];
            qq += ql[grp + (g << 4)][comp];
            xx = fmaxf(xx, xl[grp + (g << 4)][comp]);
            nn = fminf(nn, nl[grp + (g << 4)][comp]);
        }
        size_t o = (size_t)blockIdx.y * C + (blockIdx.x << 6) + t;
        ps[o] = ss; pq[o] = qq; pmx[o] = xx; pmn[o] = nn;
    }
}

__global__ __launch_bounds__(64) void stats_fin_kernel(const float* __restrict__ ps,
                                                       const float* __restrict__ pq,
                                                       int C, float invM,
                                                       const float* __restrict__ g,
                                                       const float* __restrict__ bb,
                                                       float* __restrict__ scale,
                                                       float* __restrict__ shift)
{
    int c = blockIdx.x * 64 + threadIdx.x;
    float s = 0.f, q = 0.f;
    for (int ch = 0; ch < STAT_NCH; ++ch) { s += ps[(size_t)ch * C + c]; q += pq[(size_t)ch * C + c]; }
    float m  = s * invM;
    float v  = fmaxf(q * invM - m * m, 0.f);
    float sc = g[c] / sqrtf(v + EPSBN);
    scale[c] = sc;
    shift[c] = bb[c] - m * sc;
}

// ---------- gather + bn on the fly + max + relu, C=64 f32 raw -> f16 output
// 16 points per block; 16 lanes x float4 per point row (coalesced 256B/row).
__global__ __launch_bounds__(256) void gmax1_kernel(const float* __restrict__ f,
                                                    const float* __restrict__ scale,
                                                    const float* __restrict__ shift,
                                                    const int* __restrict__ idx,
                                                    _Float16* __restrict__ agg)
{
    int t = threadIdx.x;
    int sub = t >> 4;                       // 0..15 point-within-block
    int l16 = t & 15;                       // lane-group: 4 cols
    int p = blockIdx.x * 16 + sub;
    int c = l16 << 2;
    int b = p >> 11;
    float4 sc = *(const float4*)(scale + c);
    float4 sh = *(const float4*)(shift + c);
    const int* ir = idx + (size_t)p * 16;
    const float* fb = f + ((size_t)(b << 11)) * 64;
    float4 m = {-INFINITY, -INFINITY, -INFINITY, -INFINITY};
#pragma unroll
    for (int k = 0; k < 16; ++k) {
        int nj = ir[k];
        float4 v = *(const float4*)(fb + (size_t)nj * 64 + c);
        m.x = fmaxf(m.x, fmaf(v.x, sc.x, sh.x));
        m.y = fmaxf(m.y, fmaf(v.y, sc.y, sh.y));
        m.z = fmaxf(m.z, fmaf(v.z, sc.z, sh.z));
        m.w = fmaxf(m.w, fmaf(v.w, sc.w, sh.w));
    }
    half4v o;
    o[0] = (_Float16)fmaxf(m.x, 0.f);
    o[1] = (_Float16)fmaxf(m.y, 0.f);
    o[2] = (_Float16)fmaxf(m.z, 0.f);
    o[3] = (_Float16)fmaxf(m.w, 0.f);
    *(half4v*)(agg + (size_t)p * 64 + c) = o;
}

// ------ gather(f16) + bn + max + relu, C=512 -> f16; 4 points/block,
// 64 lanes x half8 per point row (coalesced 1KB/row).
__global__ __launch_bounds__(256) void gmax2_kernel(const _Float16* __restrict__ f,
                                                    const float* __restrict__ scale,
                                                    const float* __restrict__ shift,
                                                    const int* __restrict__ idx,
                                                    _Float16* __restrict__ agg)
{
    int t = threadIdx.x;
    int sub = t >> 6;                       // 0..3 point-within-block
    int lane = t & 63;                      // 8 cols per lane
    int p = blockIdx.x * 4 + sub;
    int c = lane << 3;
    int b = p >> 11;
    float4 sc0 = *(const float4*)(scale + c);
    float4 sc1 = *(const float4*)(scale + c + 4);
    float4 sh0 = *(const float4*)(shift + c);
    float4 sh1 = *(const float4*)(shift + c + 4);
    const int* ir = idx + (size_t)p * 16;
    const _Float16* fb = f + ((size_t)(b << 11)) * 512;
    float m0 = -INFINITY, m1 = -INFINITY, m2 = -INFINITY, m3 = -INFINITY;
    float m4 = -INFINITY, m5 = -INFINITY, m6 = -INFINITY, m7 = -INFINITY;
#pragma unroll
    for (int k = 0; k < 16; ++k) {
        int nj = ir[k];
        half8 v = *(const half8*)(fb + (size_t)nj * 512 + c);
        m0 = fmaxf(m0, fmaf((float)v[0], sc0.x, sh0.x));
        m1 = fmaxf(m1, fmaf((float)v[1], sc0.y, sh0.y));
        m2 = fmaxf(m2, fmaf((float)v[2], sc0.z, sh0.z));
        m3 = fmaxf(m3, fmaf((float)v[3], sc0.w, sh0.w));
        m4 = fmaxf(m4, fmaf((float)v[4], sc1.x, sh1.x));
        m5 = fmaxf(m5, fmaf((float)v[5], sc1.y, sh1.y));
        m6 = fmaxf(m6, fmaf((float)v[6], sc1.z, sh1.z));
        m7 = fmaxf(m7, fmaf((float)v[7], sc1.w, sh1.w));
    }
    half8 o;
    o[0] = (_Float16)fmaxf(m0, 0.f); o[1] = (_Float16)fmaxf(m1, 0.f);
    o[2] = (_Float16)fmaxf(m2, 0.f); o[3] = (_Float16)fmaxf(m3, 0.f);
    o[4] = (_Float16)fmaxf(m4, 0.f); o[5] = (_Float16)fmaxf(m5, 0.f);
    o[6] = (_Float16)fmaxf(m6, 0.f); o[7] = (_Float16)fmaxf(m7, 0.f);
    *(half8*)(agg + (size_t)p * 512 + c) = o;
}

// ------- glob[b][c] from per-chunk raw max/min + BN affine (exact, monotone fmaf)
__global__ __launch_bounds__(256) void globred2_kernel(const float* __restrict__ pmx,
                                                       const float* __restrict__ pmn,
                                                       const float* __restrict__ scale,
                                                       const float* __restrict__ shift,
                                                       float* __restrict__ glob)
{
    int c = blockIdx.x * 256 + threadIdx.x;
    int b = blockIdx.y;
    float mx = -INFINITY, mn = INFINITY;
#pragma unroll
    for (int ch = 0; ch < 16; ++ch) {             // 16 chunks per batch (128 rows each)
        size_t o = (size_t)(b * 16 + ch) * 1024 + c;
        mx = fmaxf(mx, pmx[o]);
        mn = fminf(mn, pmn[o]);
    }
    float sc = scale[c], sh = shift[c];
    float v = (sc >= 0.f) ? mx : mn;
    glob[(size_t)b * 1024 + c] = fmaf(sc, v, sh);
}

// ---------------------------------------- final (8x1024)@(1024x512) + BN(8)
__global__ __launch_bounds__(256) void final_kernel(const float* __restrict__ glob,
                                                    const float* __restrict__ w2,
                                                    const float* __restrict__ g,
                                                    const float* __restrict__ bb,
                                                    float* __restrict__ out)
{
    __shared__ float vals[8][64];
    int t  = threadIdx.x;
    int c0 = blockIdx.x * 64;
    int r  = t >> 5, cl = t & 31;
    const float* gr = glob + (size_t)r * 1024;
    float a0 = 0.f, a1 = 0.f;
    int ca = c0 + cl, cb = c0 + cl + 32;
    for (int k = 0; k < 1024; ++k) {
        float gv = gr[k];
        a0 = fmaf(gv, w2[(size_t)k * 512 + ca], a0);
        a1 = fmaf(gv, w2[(size_t)k * 512 + cb], a1);
    }
    vals[r][cl] = a0; vals[r][cl + 32] = a1;
    __syncthreads();
    if (t < 64) {
        int c = c0 + t;
        float s = 0.f;
#pragma unroll
        for (int rr = 0; rr < 8; ++rr) s += vals[rr][t];
        float m = s * 0.125f;
        float v = 0.f;
#pragma unroll
        for (int rr = 0; rr < 8; ++rr) { float d = vals[rr][t] - m; v = fmaf(d, d, v); }
        v *= 0.125f;
        float sc = g[c] / sqrtf(v + EPSBN);
#pragma unroll
        for (int rr = 0; rr < 8; ++rr)
            out[(size_t)rr * 512 + c] = fmaf(vals[rr][t] - m, sc, bb[c]);
    }
}

// =============================================================== launch
extern "C" void kernel_launch(void* const* d_in, const int* in_sizes, int n_in,
                              void* d_out, int out_size, void* d_ws, size_t ws_size,
                              hipStream_t stream)
{
    const float* x   = (const float*)d_in[0];
    const float* w1a = (const float*)d_in[1];
    const float* g1a = (const float*)d_in[2];
    const float* b1a = (const float*)d_in[3];
    const float* w1b = (const float*)d_in[4];
    const float* g1b = (const float*)d_in[5];
    const float* b1b = (const float*)d_in[6];
    const float* w1c = (const float*)d_in[7];
    const float* g1c = (const float*)d_in[8];
    const float* b1c = (const float*)d_in[9];
    const float* wg1 = (const float*)d_in[10];
    const float* gg1 = (const float*)d_in[11];
    const float* bg1 = (const float*)d_in[12];
    const float* wg2 = (const float*)d_in[13];
    const float* gg2 = (const float*)d_in[14];
    const float* bg2 = (const float*)d_in[15];
    const float* w2  = (const float*)d_in[16];
    const float* g2  = (const float*)d_in[17];
    const float* b2  = (const float*)d_in[18];

    char* w = (char*)d_ws;
    size_t off = 0;
    auto take = [&](size_t bytes) -> char* {
        char* p = w + off;
        off += (bytes + 255) & ~(size_t)255;
        return p;
    };
    int*       idx     = (int*)      take((size_t)16384 * 16 * 4);
    float*     f19     = (float*)    take((size_t)16384 * 19 * 4);
    float*     h0      = (float*)    take((size_t)16384 * 64 * 4);
    float*     h1      = (float*)    take((size_t)16384 * 64 * 4);
    float*     h2      = (float*)    take((size_t)16384 * 64 * 4);
    _Float16*  f512h   = (_Float16*) take((size_t)16384 * 512 * 2);
    _Float16*  f1024h  = (_Float16*) take((size_t)16384 * 1024 * 2);
    _Float16*  aggh64  = (_Float16*) take((size_t)16384 * 64 * 2);
    _Float16*  agg512h = (_Float16*) take((size_t)16384 * 512 * 2);
    _Float16*  w1T     = (_Float16*) take((size_t)512 * 64 * 2);
    _Float16*  w2T     = (_Float16*) take((size_t)1024 * 512 * 2);
    float*     ps      = (float*)    take((size_t)STAT_NCH * 1024 * 4);
    float*     pq      = (float*)    take((size_t)STAT_NCH * 1024 * 4);
    float*     pmx     = (float*)    take((size_t)STAT_NCH * 1024 * 4);
    float*     pmn     = (float*)    take((size_t)STAT_NCH * 1024 * 4);
    float* scA  = (float*)take(64 * 4);   float* shA  = (float*)take(64 * 4);
    float* scB  = (float*)take(64 * 4);   float* shB  = (float*)take(64 * 4);
    float* scC  = (float*)take(64 * 4);   float* shC  = (float*)take(64 * 4);
    float* scG1 = (float*)take(512 * 4);  float* shG1 = (float*)take(512 * 4);
    float* scG2 = (float*)take(1024 * 4); float* shG2 = (float*)take(1024 * 4);
    float* glob = (float*)take((size_t)8 * 1024 * 4);
    (void)ws_size; (void)in_sizes; (void)n_in; (void)out_size;

    const float invM = 1.0f / 16384.0f;

    // weight conversions (depend only on inputs) + knn up front
    wtrans_kernel<<<(64 * 512 + 255) / 256, 256, 0, stream>>>(wg1, w1T, 64, 512);
    wtrans_kernel<<<(512 * 1024 + 255) / 256, 256, 0, stream>>>(wg2, w2T, 512, 1024);
    knn_kernel<<<256, 512, 0, stream>>>(x, idx);
    cov_feat_kernel<<<64, 256, 0, stream>>>(x, idx, f19);

    // L1a: 19 -> 64 (raw out) + stats
    lin19_kernel<<<4096, 256, 0, stream>>>(f19, w1a, h0);
    stats_part_kernel<<<dim3(1, STAT_NCH), 256, 0, stream>>>(h0, 64, ps, pq);
    stats_fin_kernel<<<1, 64, 0, stream>>>(ps, pq, 64, invM, g1a, b1a, scA, shA);

    // L1b: bn_relu(h0) @ w1b -> h1 raw, stats on h1
    gemm_bn_kernel<<<dim3(1, 256), 256, 0, stream>>>(h0, w1b, h1, scA, shA, 16384, 64, 64);
    stats_part_kernel<<<dim3(1, STAT_NCH), 256, 0, stream>>>(h1, 64, ps, pq);
    stats_fin_kernel<<<1, 64, 0, stream>>>(ps, pq, 64, invM, g1b, b1b, scB, shB);

    // L1c: bn_relu(h1) @ w1c -> h2 raw, stats on h2
    gemm_bn_kernel<<<dim3(1, 256), 256, 0, stream>>>(h1, w1c, h2, scB, shB, 16384, 64, 64);
    stats_part_kernel<<<dim3(1, STAT_NCH), 256, 0, stream>>>(h2, 64, ps, pq);
    stats_fin_kernel<<<1, 64, 0, stream>>>(ps, pq, 64, invM, g1c, b1c, scC, shC);

    // graph pool 1: gather(bn(h2))-max-relu(f16) then f16 MFMA 64->512 (f16 out)
    gmax1_kernel<<<1024, 256, 0, stream>>>(h2, scC, shC, idx, aggh64);
    hgemm_kernel<<<dim3(4, 128), 256, 0, stream>>>(aggh64, w1T, f512h, 16384, 512, 64);
    stats_part_h_kernel<<<dim3(8, STAT_NCH), 256, 0, stream>>>(f512h, 512, ps, pq);
    stats_fin_kernel<<<8, 64, 0, stream>>>(ps, pq, 512, invM, gg1, bg1, scG1, shG1);

    // graph pool 2: gather(bn)-max-relu(f16) then f16 MFMA 512->1024 (f16 out)
    gmax2_kernel<<<4096, 256, 0, stream>>>(f512h, scG1, shG1, idx, agg512h);
    hgemm_kernel<<<dim3(8, 128), 256, 0, stream>>>(agg512h, w2T, f1024h, 16384, 1024, 512);
    stats_minmax_part_h_kernel<<<dim3(16, STAT_NCH), 256, 0, stream>>>(f1024h, 1024, ps, pq, pmx, pmn);
    stats_fin_kernel<<<16, 64, 0, stream>>>(ps, pq, 1024, invM, gg2, bg2, scG2, shG2);

    // global max via per-chunk raw max/min + affine (exact)
    globred2_kernel<<<dim3(4, 8), 256, 0, stream>>>(pmx, pmn, scG2, shG2, glob);

    // final linear + BN over 8 rows
    final_kernel<<<8, 256, 0, stream>>>(glob, w2, g2, b2, (float*)d_out);
}